// Round 16
// baseline (500.867 us; speedup 1.0000x reference)
//
#include <hip/hip_runtime.h>

// NucleiGNN fused forward. r15: live (F32-input) path at 388us hot,
// absmax 0.03125; occupancy pinned at 1 WG/CU across ALL configs
// (LDS 54-145KB, VGPR 76-160, 256/512 thr) -> stop chasing residency.
// r5-r12 structural nulls were measured on the DEAD BF16 path; the
// 2-molecule fusion has never run live. This round (live): TWO molecules
// per 512-thread block (grid 1024), mfma_dense2 feeds BOTH mols from ONE
// B-fragment load (half wpack L2 traffic, 8 indep MFMA chains/load), and
// every barrier phase carries 2x independent work -> per-phase stalls
// amortized. LDS 108.8KB (1 WG/CU by design). launch_bounds(512,1):
// up to 256 VGPR free at 2 waves/SIMD.
// Numerics = r15 (verified 0.03125): activations/k/vT/P single-bf16,
// weights hi+lo (dense 2-term Ah*Bh+Ah*Bl), logits/PV 1-term,
// P staged in dead k region (2KB swizzled/wave/mol).

#define NBATCH 2048
#define NATOM  64
#define NF     128
#define NLAYER 3
#define STR    132   // f32 scratch row stride
#define ASTRB  136   // bf16 row-major tile stride
#define VSTR   72    // vT row stride
#define NTH    512
#define MOLS   2
// per-mol bf16 elems: a 8704 + k 8704 + vt 9216 = 26624 (53248 B)
#define MOLELT 26624

using bf16x8 = __attribute__((ext_vector_type(8))) __bf16;
using bf16x4 = __attribute__((ext_vector_type(4))) __bf16;
using f32x4  = __attribute__((ext_vector_type(4))) float;

__device__ __forceinline__ float bf2f(unsigned short u) {
    union { unsigned int i; float f; } v; v.i = ((unsigned int)u) << 16; return v.f;
}
__device__ __forceinline__ unsigned short f2bf(float f) {
    union { float ff; unsigned int i; } v; v.ff = f;
    unsigned int x = v.i;
    if ((x & 0x7f800000u) == 0x7f800000u) return (unsigned short)(x >> 16);
    return (unsigned short)((x + 0x7fffu + ((x >> 16) & 1u)) >> 16);
}
__device__ __forceinline__ unsigned short bfbits(float x) {
    union { __bf16 b; unsigned short u; } v; v.b = (__bf16)x; return v.u;
}

__device__ __forceinline__ float fast_rcp(float x)  { return __builtin_amdgcn_rcpf(x); }
__device__ __forceinline__ float fast_sqrt(float x) { return __builtin_amdgcn_sqrtf(x); }
__device__ __forceinline__ float fast_exp(float x)  { return __builtin_amdgcn_exp2f(x * 1.4426950408889634f); }

template<bool BF16>
__device__ __forceinline__ float ldT(const void* p, int i) {
    if constexpr (BF16) return bf2f(((const unsigned short*)p)[i]);
    else                return ((const float*)p)[i];
}
template<bool BF16>
__device__ __forceinline__ float4 ld4T(const void* p, int i) {
    if constexpr (BF16) {
        ushort4 v = *(const ushort4*)((const unsigned short*)p + i);
        return make_float4(bf2f(v.x), bf2f(v.y), bf2f(v.z), bf2f(v.w));
    } else {
        return *(const float4*)((const float*)p + i);
    }
}

// LN row statistics; 32 consecutive lanes share a row.
__device__ __forceinline__ void ln_stats(const float (&h)[4][4], float (&mu)[4], float (&rs)[4]) {
    #pragma unroll
    for (int i = 0; i < 4; ++i) {
        float s  = h[i][0] + h[i][1] + h[i][2] + h[i][3];
        float s2 = h[i][0]*h[i][0] + h[i][1]*h[i][1] + h[i][2]*h[i][2] + h[i][3]*h[i][3];
        #pragma unroll
        for (int m = 1; m <= 16; m <<= 1) {
            s  += __shfl_xor(s,  m);
            s2 += __shfl_xor(s2, m);
        }
        float mm = s * (1.f / 128.f);
        float vv = s2 * (1.f / 128.f) - mm * mm;
        mu[i] = mm;
        rs[i] = rsqrtf(fmaxf(vv, 0.f) + 1e-5f);
    }
}

// normalize h with (mu,rs), store single-bf16 into A tile
__device__ __forceinline__ void write_a(const float (&h)[4][4], const float (&mu)[4], const float (&rs)[4],
                                        __bf16* __restrict__ a_hi, int r0, int fq) {
    #pragma unroll
    for (int i = 0; i < 4; ++i) {
        bf16x4 v;
        #pragma unroll
        for (int jj = 0; jj < 4; ++jj)
            v[jj] = (__bf16)((h[i][jj] - mu[i]) * rs[i]);
        *(bf16x4*)&a_hi[(r0 + i) * ASTRB + fq * 4] = v;
    }
}

// Fused dense for TWO molecules: one B-fragment load feeds both.
// [64,128]x[128,128], 2x2 tiles/wave each. WLO adds Ah*Bl weight term.
template<bool WLO>
__device__ __forceinline__ void mfma_dense2(const __bf16* __restrict__ a0,
                                            const __bf16* __restrict__ a1,
                                            const __bf16* __restrict__ bp,
                                            f32x4 (&acc)[MOLS][2][2], int lane, int wave)
{
    const int R0  = (wave >> 2) << 5;
    const int Cq2 = (wave & 3) << 1;
    const int c = lane & 15, g = lane >> 4;
    const __bf16* bl = bp + 16384;
    #pragma unroll
    for (int m = 0; m < MOLS; ++m)
        #pragma unroll
        for (int t2 = 0; t2 < 2; ++t2)
            #pragma unroll
            for (int j = 0; j < 2; ++j)
                acc[m][t2][j] = (f32x4){0.f, 0.f, 0.f, 0.f};
    #pragma unroll
    for (int kc = 0; kc < 4; ++kc) {
        const int ao = kc * 32 + (g << 3);
        bf16x8 a00 = *(const bf16x8*)&a0[(R0 + c) * ASTRB + ao];
        bf16x8 a01 = *(const bf16x8*)&a0[(R0 + 16 + c) * ASTRB + ao];
        bf16x8 a10 = *(const bf16x8*)&a1[(R0 + c) * ASTRB + ao];
        bf16x8 a11 = *(const bf16x8*)&a1[(R0 + 16 + c) * ASTRB + ao];
        #pragma unroll
        for (int j = 0; j < 2; ++j) {
            const int bi = ((((kc << 3) + Cq2 + j) << 6) + lane) << 3;
            bf16x8 bh = *(const bf16x8*)&bp[bi];
            acc[0][0][j] = __builtin_amdgcn_mfma_f32_16x16x32_bf16(a00, bh, acc[0][0][j], 0, 0, 0);
            acc[1][0][j] = __builtin_amdgcn_mfma_f32_16x16x32_bf16(a10, bh, acc[1][0][j], 0, 0, 0);
            acc[0][1][j] = __builtin_amdgcn_mfma_f32_16x16x32_bf16(a01, bh, acc[0][1][j], 0, 0, 0);
            acc[1][1][j] = __builtin_amdgcn_mfma_f32_16x16x32_bf16(a11, bh, acc[1][1][j], 0, 0, 0);
            if constexpr (WLO) {
                bf16x8 bv = *(const bf16x8*)&bl[bi];
                acc[0][0][j] = __builtin_amdgcn_mfma_f32_16x16x32_bf16(a00, bv, acc[0][0][j], 0, 0, 0);
                acc[1][0][j] = __builtin_amdgcn_mfma_f32_16x16x32_bf16(a10, bv, acc[1][0][j], 0, 0, 0);
                acc[0][1][j] = __builtin_amdgcn_mfma_f32_16x16x32_bf16(a01, bv, acc[0][1][j], 0, 0, 0);
                acc[1][1][j] = __builtin_amdgcn_mfma_f32_16x16x32_bf16(a11, bv, acc[1][1][j], 0, 0, 0);
            }
        }
    }
}

// C (2x2 tiles) -> single-bf16 row-major [64][ASTRB]
__device__ __forceinline__ void writeC_rm(const f32x4 (&acc)[2][2],
                                          __bf16* __restrict__ hi, int lane, int wave)
{
    const int R0 = (wave >> 2) << 5;
    const int C0 = (wave & 3) << 5;
    const int c = lane & 15, g4 = (lane >> 4) << 2;
    #pragma unroll
    for (int t2 = 0; t2 < 2; ++t2)
    #pragma unroll
    for (int j = 0; j < 2; ++j)
    #pragma unroll
    for (int r = 0; r < 4; ++r)
        hi[(R0 + 16*t2 + g4 + r) * ASTRB + C0 + 16*j + c] = (__bf16)acc[t2][j][r];
}

// C (2x2 tiles) -> single-bf16 TRANSPOSED vT[d][m]
__device__ __forceinline__ void writeC_vt(const f32x4 (&acc)[2][2],
                                          __bf16* __restrict__ hi, int lane, int wave)
{
    const int R0 = (wave >> 2) << 5;   // m rows
    const int C0 = (wave & 3) << 5;    // d cols
    const int c = lane & 15, g4 = (lane >> 4) << 2;
    #pragma unroll
    for (int t2 = 0; t2 < 2; ++t2)
    #pragma unroll
    for (int j = 0; j < 2; ++j)
    #pragma unroll
    for (int r = 0; r < 4; ++r) {
        int m = R0 + 16*t2 + g4 + r, d = C0 + 16*j + c;
        hi[d * VSTR + m] = (__bf16)acc[t2][j][r];
    }
}

// C (2x2 tiles) -> f32 scratch [64][STR]
__device__ __forceinline__ void writeC_f32(const f32x4 (&acc)[2][2],
                                           float* __restrict__ dst, int lane, int wave)
{
    const int R0 = (wave >> 2) << 5;
    const int C0 = (wave & 3) << 5;
    const int c = lane & 15, g4 = (lane >> 4) << 2;
    #pragma unroll
    for (int t2 = 0; t2 < 2; ++t2)
    #pragma unroll
    for (int j = 0; j < 2; ++j)
    #pragma unroll
    for (int r = 0; r < 4; ++r)
        dst[(R0 + 16*t2 + g4 + r) * STR + C0 + 16*j + c] = acc[t2][j][r];
}

// Pre-split weights into bf16 hi/lo, packed in MFMA B-fragment order.
// Slot layout: wpack[(kind*3 + l)*32768]: [0,16384)=hi frags, [16384,32768)=lo.
template<bool BF16>
__global__ __launch_bounds__(256)
void prep_w(const void* __restrict__ Wq, const void* __restrict__ Wk,
            const void* __restrict__ Wv, const void* __restrict__ Wo,
            const void* __restrict__ Wf, unsigned short* __restrict__ wpack)
{
    {
        const unsigned int* w = (const unsigned int*)Wq;
        bool isbf = true;
        #pragma unroll
        for (int i = 0; i < 16; ++i) {
            unsigned int e = (w[i] >> 7) & 0xFFu;
            isbf = isbf && (e >= 0x60u && e <= 0x7Eu);
        }
        if (isbf != BF16) return;
    }
    const int mat  = blockIdx.x;            // 0..14 = kind*3 + l
    const int kind = mat / 3, l = mat % 3;
    const void* src = (kind == 0) ? Wq : (kind == 1) ? Wk : (kind == 2) ? Wv
                    : (kind == 3) ? Wo : Wf;
    unsigned short* dh = wpack + (size_t)mat * 32768;
    unsigned short* dl = dh + 16384;
    for (int f = threadIdx.x; f < 16384; f += 256) {
        int e    = f & 7;
        int lane = (f >> 3) & 63;
        int tj   = (f >> 9) & 7;
        int kc   = f >> 12;
        int row  = kc * 32 + ((lane >> 4) << 3) + e;
        int col  = tj * 16 + (lane & 15);
        float x  = ldT<BF16>(src, (l * NF + row) * NF + col);
        unsigned short hi = f2bf(x);
        unsigned short lo = f2bf(x - bf2f(hi));
        dh[f] = hi; dl[f] = lo;
    }
}

// 2 mols x 26624 bf16 + cs[2][256]f + wel 48f + lenp
static constexpr size_t SMEM_BYTES =
    (size_t)MOLS * MOLELT * 2 + (MOLS * 256 + 48) * 4 + 16;   // 108752 B

template<bool BF16>
__global__ __launch_bounds__(NTH, 1)
void gnn_fused(const void* __restrict__ coords,
               const int* __restrict__ species,
               const unsigned char* __restrict__ maskraw,
               const void* __restrict__ embed,
               const void* __restrict__ Wq,          // dtype signature only
               const void* __restrict__ We,
               const void* __restrict__ bfb,
               const unsigned short* __restrict__ wpack,
               void* __restrict__ out)
{
    constexpr bool WLO = !BF16;   // weight-lo compensation on the f32 path
    // ---- dtype signature check (block-uniform; wrong instantiation exits) ----
    {
        const unsigned int* w = (const unsigned int*)Wq;
        bool isbf = true;
        #pragma unroll
        for (int i = 0; i < 16; ++i) {
            unsigned int e = (w[i] >> 7) & 0xFFu;
            isbf = isbf && (e >= 0x60u && e <= 0x7Eu);
        }
        if (isbf != BF16) return;
    }

    extern __shared__ __bf16 sm[];
    __bf16 *a_hi[MOLS], *k_hi[MOLS], *vt_hi[MOLS];
    float  *scratch[MOLS], *csp[MOLS];
    float* tailf = (float*)(sm + MOLS * MOLELT);
    #pragma unroll
    for (int m = 0; m < MOLS; ++m) {
        __bf16* base = sm + m * MOLELT;
        a_hi[m]  = base;            // [64][136] hn/q/msg
        k_hi[m]  = base + 8704;     // [64][136] k (P + scratch overlay)
        vt_hi[m] = base + 17408;    // [128][72] v transposed
        scratch[m] = (float*)k_hi[m];   // spans k+vt: 35840B >= 33792B
        csp[m] = tailf + m * 256;
    }
    float* wel  = tailf + MOLS * 256;
    int*   lenp = (int*)(wel + 48);

    const int t    = threadIdx.x;
    const int b    = blockIdx.x;
    const int fq   = t & 31;
    const int r0   = (t >> 5) * 4;
    const int lane = t & 63;
    const int wave = t >> 6;
    const int c    = lane & 15;
    const int g    = lane >> 4;
    const int g4   = g << 2;
    const int hd   = wave >> 2;          // attention head of this wave
    const int wb   = (wave & 3) << 4;    // attention row base of this wave

    // ---- init: coords (per mol), We, mask lengths ----
    if (t < 64 * MOLS) {
        int tl = t & 63;
        float* csm = tailf + (t >> 6) * 256;
        int gi = (b * MOLS + (t >> 6)) * NATOM + tl;
        csm[tl * 4 + 0] = ldT<BF16>(coords, gi * 3 + 0);
        csm[tl * 4 + 1] = ldT<BF16>(coords, gi * 3 + 1);
        csm[tl * 4 + 2] = ldT<BF16>(coords, gi * 3 + 2);
    }
    if (t >= 64 * MOLS && t < 64 * MOLS + 42) wel[t - 64 * MOLS] = ldT<BF16>(We, t - 64 * MOLS);
    if (t < 64 * MOLS) {
        int tl = t & 63, mm = t >> 6;
        int gi = (b * MOLS + mm) * NATOM + tl;
        unsigned int w0 = *(const unsigned int*)maskraw;
        bool f;
        if (w0 == 1u)               f = ((const int*)maskraw)[gi] != 0;
        else if (w0 == 0x01010101u) f = maskraw[gi] != 0;
        else if (w0 == 0x3F800000u) f = ((const float*)maskraw)[gi] != 0.f;
        else                        f = ((const unsigned short*)maskraw)[gi] != 0;
        unsigned long long bal = __ballot(f);
        if (tl == 0) lenp[mm] = (int)__popcll(bal);
    }

    // ---- h0 = embed[species-1] per mol ----
    float h[MOLS][4][4];
    #pragma unroll
    for (int m = 0; m < MOLS; ++m)
        #pragma unroll
        for (int i = 0; i < 4; ++i) {
            int sp = species[(b * MOLS + m) * NATOM + r0 + i];
            float4 ev = ld4T<BF16>(embed, (sp - 1) * NF + fq * 4);
            h[m][i][0] = ev.x; h[m][i][1] = ev.y; h[m][i][2] = ev.z; h[m][i][3] = ev.w;
        }
    __syncthreads();
    int len[MOLS];
    #pragma unroll
    for (int m = 0; m < MOLS; ++m) len[m] = lenp[m];
    #pragma unroll
    for (int m = 0; m < MOLS; ++m)
        #pragma unroll
        for (int i = 0; i < 4; ++i)
            if (r0 + i >= len[m]) { h[m][i][0]=0.f; h[m][i][1]=0.f; h[m][i][2]=0.f; h[m][i][3]=0.f; }

    float mu[4], rs[4];
    for (int l = 0; l < NLAYER; ++l) {
        // hn = LN(h) -> single-bf16 A tiles
        #pragma unroll
        for (int m = 0; m < MOLS; ++m) {
            ln_stats(h[m], mu, rs);
            write_a(h[m], mu, rs, a_hi[m], r0, fq);
        }
        __syncthreads();                                        // B1

        // k (both mols, one B stream); vT (both); q (both, held in regs)
        {
            f32x4 kacc[MOLS][2][2];
            mfma_dense2<WLO>(a_hi[0], a_hi[1], (const __bf16*)wpack + (size_t)(3 + l) * 32768, kacc, lane, wave);
            writeC_rm(kacc[0], k_hi[0], lane, wave);
            writeC_rm(kacc[1], k_hi[1], lane, wave);
        }
        {
            f32x4 vacc[MOLS][2][2];
            mfma_dense2<WLO>(a_hi[0], a_hi[1], (const __bf16*)wpack + (size_t)(6 + l) * 32768, vacc, lane, wave);
            writeC_vt(vacc[0], vt_hi[0], lane, wave);
            writeC_vt(vacc[1], vt_hi[1], lane, wave);
        }
        f32x4 qacc[MOLS][2][2];
        mfma_dense2<WLO>(a_hi[0], a_hi[1], (const __bf16*)wpack + (size_t)(0 + l) * 32768, qacc, lane, wave);
        __syncthreads();                                        // B2: a-reads done
        writeC_rm(qacc[0], a_hi[0], lane, wave);
        writeC_rm(qacc[1], a_hi[1], lane, wave);
        __syncthreads();                                        // B3: q/k/vT visible

        // ---- logits (per mol; NT: k row-major IS B-frag), 1-term ----
        f32x4 lacc[MOLS][4];
        #pragma unroll
        for (int m = 0; m < MOLS; ++m) {
            #pragma unroll
            for (int jt = 0; jt < 4; ++jt) lacc[m][jt] = (f32x4){0.f,0.f,0.f,0.f};
            #pragma unroll
            for (int kc = 0; kc < 2; ++kc) {
                const int qo = (wb + c) * ASTRB + hd * 64 + kc * 32 + (g << 3);
                bf16x8 qh = *(const bf16x8*)&a_hi[m][qo];
                #pragma unroll
                for (int jt = 0; jt < 4; ++jt) {
                    const int ko = (jt * 16 + c) * ASTRB + hd * 64 + kc * 32 + (g << 3);
                    bf16x8 kh = *(const bf16x8*)&k_hi[m][ko];
                    lacc[m][jt] = __builtin_amdgcn_mfma_f32_16x16x32_bf16(qh, kh, lacc[m][jt], 0, 0, 0);
                }
            }
        }
        __syncthreads();   // B4: q/k reads drained -> P may overwrite k, msg may overwrite q

        // ---- per mol: edge bias + softmax + P stage + PV + msg ----
        float we_[7];
        #pragma unroll
        for (int e = 0; e < 7; ++e) we_[e] = wel[l * 14 + e * 2 + hd];
        #pragma unroll
        for (int m = 0; m < MOLS; ++m) {
            float* cs = csp[m];
            float cnx[4], cny[4], cnz[4];
            #pragma unroll
            for (int r = 0; r < 4; ++r) {
                int n = wb + g4 + r;
                cnx[r] = cs[n*4]; cny[r] = cs[n*4+1]; cnz[r] = cs[n*4+2];
            }
            float lg[4][4];
            #pragma unroll
            for (int jt = 0; jt < 4; ++jt) {
                int mc = jt * 16 + c;
                float cmx = cs[mc*4], cmy = cs[mc*4+1], cmz = cs[mc*4+2];
                #pragma unroll
                for (int r = 0; r < 4; ++r) {
                    float dx = cnx[r]-cmx, dy = cny[r]-cmy, dz = cnz[r]-cmz;
                    float d  = fast_sqrt(dx*dx + dy*dy + dz*dz + 1e-12f);
                    float et = fast_exp(-d);
                    float s1 = fast_rcp(1.f + 7.38905609893065f   * et);
                    float s2 = fast_rcp(1.f + 54.598150033144236f * et);
                    float s3 = fast_rcp(1.f + 403.4287934927351f  * et);
                    lg[jt][r] = lacc[m][jt][r] * 0.125f
                              + dx*we_[0] + dy*we_[1] + dz*we_[2] + d*we_[3]
                              + s1*we_[4] + s2*we_[5] + s3*we_[6];
                }
            }
            float mx[4] = {-3e38f, -3e38f, -3e38f, -3e38f};
            #pragma unroll
            for (int jt = 0; jt < 4; ++jt)
                if (jt * 16 + c < len[m]) {
                    #pragma unroll
                    for (int r = 0; r < 4; ++r) mx[r] = fmaxf(mx[r], lg[jt][r]);
                }
            #pragma unroll
            for (int r = 0; r < 4; ++r) {
                mx[r] = fmaxf(mx[r], __shfl_xor(mx[r], 1));
                mx[r] = fmaxf(mx[r], __shfl_xor(mx[r], 2));
                mx[r] = fmaxf(mx[r], __shfl_xor(mx[r], 4));
                mx[r] = fmaxf(mx[r], __shfl_xor(mx[r], 8));
            }
            float sv[4] = {0.f, 0.f, 0.f, 0.f};
            #pragma unroll
            for (int jt = 0; jt < 4; ++jt) {
                bool vm = (jt * 16 + c) < len[m];
                #pragma unroll
                for (int r = 0; r < 4; ++r) {
                    float e = vm ? fast_exp(lg[jt][r] - mx[r]) : 0.f;
                    lg[jt][r] = e; sv[r] += e;
                }
            }
            #pragma unroll
            for (int r = 0; r < 4; ++r) {
                sv[r] += __shfl_xor(sv[r], 1);
                sv[r] += __shfl_xor(sv[r], 2);
                sv[r] += __shfl_xor(sv[r], 4);
                sv[r] += __shfl_xor(sv[r], 8);
            }
            float inv[4];
            #pragma unroll
            for (int r = 0; r < 4; ++r)
                inv[r] = (wb + g4 + r < len[m]) ? fast_rcp(sv[r]) : 0.f;

            // P stage: single-bf16, 2KB swizzled per wave in dead k[m] region
            // elem (x=0..15, mm2=0..63): byte = x*128 + ((mm2*2) ^ ((x&7)<<4))
            {
                char* pw = (char*)k_hi[m] + wave * 2048;
                #pragma unroll
                for (int jt = 0; jt < 4; ++jt)
                    #pragma unroll
                    for (int r = 0; r < 4; ++r) {
                        int x = g4 + r, mm2 = jt * 16 + c;
                        *(__bf16*)(pw + x * 128 + ((mm2 * 2) ^ ((x & 7) << 4))) =
                            (__bf16)(lg[jt][r] * inv[r]);
                    }
            }
            // no barrier: P write->read is same-wave (lgkmcnt-ordered)

            // PV (1-term)
            f32x4 macc[4];
            #pragma unroll
            for (int jt = 0; jt < 4; ++jt) macc[jt] = (f32x4){0.f,0.f,0.f,0.f};
            #pragma unroll
            for (int kc = 0; kc < 2; ++kc) {
                const char* pw = (const char*)k_hi[m] + wave * 2048;
                const int m0 = kc * 32 + (g << 3);
                bf16x8 ph = *(const bf16x8*)(pw + c * 128 + ((m0 * 2) ^ ((c & 7) << 4)));
                #pragma unroll
                for (int jt = 0; jt < 4; ++jt) {
                    const int vo = (hd * 64 + jt * 16 + c) * VSTR + kc * 32 + (g << 3);
                    bf16x8 vh = *(const bf16x8*)&vt_hi[m][vo];
                    macc[jt] = __builtin_amdgcn_mfma_f32_16x16x32_bf16(ph, vh, macc[jt], 0, 0, 0);
                }
            }
            // msg -> a[m] single-bf16 (q dead since B4)
            #pragma unroll
            for (int jt = 0; jt < 4; ++jt)
                #pragma unroll
                for (int r = 0; r < 4; ++r) {
                    int idx = (wb + g4 + r) * ASTRB + hd * 64 + jt * 16 + c;
                    a_hi[m][idx] = (__bf16)macc[jt][r];
                }
        }
        __syncthreads();                                        // B5: msg visible; k/vt/P dead

        // h += msg @ Wo (both mols, one B stream; scratch overlays dead k/P+vt)
        {
            f32x4 oacc[MOLS][2][2];
            mfma_dense2<WLO>(a_hi[0], a_hi[1], (const __bf16*)wpack + (size_t)(9 + l) * 32768, oacc, lane, wave);
            writeC_f32(oacc[0], scratch[0], lane, wave);
            writeC_f32(oacc[1], scratch[1], lane, wave);
        }
        __syncthreads();                                        // B6
        #pragma unroll
        for (int m = 0; m < MOLS; ++m)
            #pragma unroll
            for (int i = 0; i < 4; ++i) {
                float4 ov = *(const float4*)&scratch[m][(r0 + i) * STR + fq * 4];
                h[m][i][0] += ov.x; h[m][i][1] += ov.y; h[m][i][2] += ov.z; h[m][i][3] += ov.w;
            }

        // h += tanh(LN(h) @ Wf + bf)
        #pragma unroll
        for (int m = 0; m < MOLS; ++m) {
            ln_stats(h[m], mu, rs);
            write_a(h[m], mu, rs, a_hi[m], r0, fq);
        }
        __syncthreads();                                        // B7
        {
            f32x4 facc[MOLS][2][2];
            mfma_dense2<WLO>(a_hi[0], a_hi[1], (const __bf16*)wpack + (size_t)(12 + l) * 32768, facc, lane, wave);
            writeC_f32(facc[0], scratch[0], lane, wave);
            writeC_f32(facc[1], scratch[1], lane, wave);
        }
        __syncthreads();                                        // B8
        {
            float4 bv = ld4T<BF16>(bfb, l * NF + fq * 4);
            #pragma unroll
            for (int m = 0; m < MOLS; ++m)
                #pragma unroll
                for (int i = 0; i < 4; ++i) {
                    float z0 = scratch[m][(r0 + i) * STR + fq * 4 + 0] + bv.x;
                    float z1 = scratch[m][(r0 + i) * STR + fq * 4 + 1] + bv.y;
                    float z2 = scratch[m][(r0 + i) * STR + fq * 4 + 2] + bv.z;
                    float z3 = scratch[m][(r0 + i) * STR + fq * 4 + 3] + bv.w;
                    // tanh(z) = 1 - 2/(e^{2z}+1)
                    h[m][i][0] += 1.f - 2.f * fast_rcp(fast_exp(2.f*z0) + 1.f);
                    h[m][i][1] += 1.f - 2.f * fast_rcp(fast_exp(2.f*z1) + 1.f);
                    h[m][i][2] += 1.f - 2.f * fast_rcp(fast_exp(2.f*z2) + 1.f);
                    h[m][i][3] += 1.f - 2.f * fast_rcp(fast_exp(2.f*z3) + 1.f);
                }
        }
        // h *= mask
        #pragma unroll
        for (int m = 0; m < MOLS; ++m)
            #pragma unroll
            for (int i = 0; i < 4; ++i)
                if (r0 + i >= len[m]) { h[m][i][0]=0.f; h[m][i][1]=0.f; h[m][i][2]=0.f; h[m][i][3]=0.f; }
        // next write_a safe: Wf a-reads done before B8; scratch tanh reads
        // finish before next B1.
    }

    // out = LN(h), per mol
    #pragma unroll
    for (int m = 0; m < MOLS; ++m) {
        ln_stats(h[m], mu, rs);
        #pragma unroll
        for (int i = 0; i < 4; ++i) {
            int idx = (b * MOLS + m) * NATOM * NF + (r0 + i) * NF + fq * 4;
            float o0 = (h[m][i][0]-mu[i])*rs[i], o1 = (h[m][i][1]-mu[i])*rs[i];
            float o2 = (h[m][i][2]-mu[i])*rs[i], o3 = (h[m][i][3]-mu[i])*rs[i];
            if constexpr (BF16) {
                ushort4 o;
                o.x = bfbits(o0); o.y = bfbits(o1); o.z = bfbits(o2); o.w = bfbits(o3);
                *(ushort4*)((unsigned short*)out + idx) = o;
            } else {
                *(float4*)((float*)out + idx) = make_float4(o0, o1, o2, o3);
            }
        }
    }
}

extern "C" void kernel_launch(void* const* d_in, const int* in_sizes, int n_in,
                              void* d_out, int out_size, void* d_ws, size_t ws_size,
                              hipStream_t stream) {
    const void*           coords  = d_in[0];
    const int*            species = (const int*)d_in[1];
    const unsigned char*  maskraw = (const unsigned char*)d_in[2];
    const void*           embed   = d_in[3];
    const void*           Wq      = d_in[4];
    const void*           Wk      = d_in[5];
    const void*           Wv      = d_in[6];
    const void*           Wo      = d_in[7];
    const void*           We      = d_in[8];
    const void*           Wf      = d_in[9];
    const void*           bfb     = d_in[10];

    unsigned short* wpack = (unsigned short*)d_ws;   // 15 * 32768 ushorts = 960 KB

    (void)hipFuncSetAttribute((const void*)gnn_fused<true>,
                              hipFuncAttributeMaxDynamicSharedMemorySize,
                              (int)SMEM_BYTES);
    (void)hipFuncSetAttribute((const void*)gnn_fused<false>,
                              hipFuncAttributeMaxDynamicSharedMemorySize,
                              (int)SMEM_BYTES);

    prep_w<true ><<<dim3(15), dim3(256), 0, stream>>>(Wq, Wk, Wv, Wo, Wf, wpack);
    prep_w<false><<<dim3(15), dim3(256), 0, stream>>>(Wq, Wk, Wv, Wo, Wf, wpack);

    gnn_fused<true ><<<dim3(NBATCH / MOLS), dim3(NTH), SMEM_BYTES, stream>>>(
        coords, species, maskraw, embed, Wq, We, bfb, wpack, d_out);
    gnn_fused<false><<<dim3(NBATCH / MOLS), dim3(NTH), SMEM_BYTES, stream>>>(
        coords, species, maskraw, embed, Wq, We, bfb, wpack, d_out);
}

// Round 17
// 422.275 us; speedup vs baseline: 1.1861x; 1.1861x over previous
//
#include <hip/hip_runtime.h>

// NucleiGNN fused forward. Live (F32-input) path history: r13 427us,
// r15 388us hot; r16 2-mol fusion spilled and regressed (426, FETCH 4x).
// This round: r15 skeleton with
//  (1) 8 -> 6 barriers/layer: q and P get their OWN LDS buffers (LDS
//      88.3KB -- free, occupancy is pinned 1 WG/CU at 54/72/145KB alike),
//      removing the q-in-regs drain barrier and the post-logits drain.
//  (2) d/exp(-d) register cache restored (32 VGPR, ~112 total): kills
//      96 quarter-rate transcendentals/thread on the softmax phase.
// Numerics = r15 (verified absmax 0.03125): activations/k/vT/P single-
// bf16; weights hi+lo (dense 2-term Ah*Bh+Ah*Bl); logits/PV 1-term.
// Barrier audit per layer: B1 a-ready -> dense k/v/q (read a; write
// k,vt,q bufs) -> B2 kqv-visible -> logits(q,k) + softmax + P(own buf,
// same-wave) + PV(vt) + msg->a (a dead: all a-readers pre-B2) -> B3
// msg-visible (k,vt,P dead) -> Wo(a)->scratch(overlays k+vt) -> B4 ->
// h+=scratch, LN, write_a (Wo a-reads pre-B4) -> B5 a-ready -> Wf ->
// scratch (h-update reads pre-B5) -> B6 -> tanh (next write_a after
// tanh; Wf a-reads pre-B6).

#define NBATCH 2048
#define NATOM  64
#define NF     128
#define NLAYER 3
#define STR    132   // f32 scratch row stride
#define ASTRB  136   // bf16 row-major tile stride
#define VSTR   72    // vT row stride
#define NTH    512

using bf16x8 = __attribute__((ext_vector_type(8))) __bf16;
using bf16x4 = __attribute__((ext_vector_type(4))) __bf16;
using f32x4  = __attribute__((ext_vector_type(4))) float;

__device__ __forceinline__ float bf2f(unsigned short u) {
    union { unsigned int i; float f; } v; v.i = ((unsigned int)u) << 16; return v.f;
}
__device__ __forceinline__ unsigned short f2bf(float f) {
    union { float ff; unsigned int i; } v; v.ff = f;
    unsigned int x = v.i;
    if ((x & 0x7f800000u) == 0x7f800000u) return (unsigned short)(x >> 16);
    return (unsigned short)((x + 0x7fffu + ((x >> 16) & 1u)) >> 16);
}
__device__ __forceinline__ unsigned short bfbits(float x) {
    union { __bf16 b; unsigned short u; } v; v.b = (__bf16)x; return v.u;
}

__device__ __forceinline__ float fast_rcp(float x)  { return __builtin_amdgcn_rcpf(x); }
__device__ __forceinline__ float fast_sqrt(float x) { return __builtin_amdgcn_sqrtf(x); }
__device__ __forceinline__ float fast_exp(float x)  { return __builtin_amdgcn_exp2f(x * 1.4426950408889634f); }

template<bool BF16>
__device__ __forceinline__ float ldT(const void* p, int i) {
    if constexpr (BF16) return bf2f(((const unsigned short*)p)[i]);
    else                return ((const float*)p)[i];
}
template<bool BF16>
__device__ __forceinline__ float4 ld4T(const void* p, int i) {
    if constexpr (BF16) {
        ushort4 v = *(const ushort4*)((const unsigned short*)p + i);
        return make_float4(bf2f(v.x), bf2f(v.y), bf2f(v.z), bf2f(v.w));
    } else {
        return *(const float4*)((const float*)p + i);
    }
}

// LN row statistics; 32 consecutive lanes share a row.
__device__ __forceinline__ void ln_stats(const float (&h)[4][4], float (&mu)[4], float (&rs)[4]) {
    #pragma unroll
    for (int i = 0; i < 4; ++i) {
        float s  = h[i][0] + h[i][1] + h[i][2] + h[i][3];
        float s2 = h[i][0]*h[i][0] + h[i][1]*h[i][1] + h[i][2]*h[i][2] + h[i][3]*h[i][3];
        #pragma unroll
        for (int m = 1; m <= 16; m <<= 1) {
            s  += __shfl_xor(s,  m);
            s2 += __shfl_xor(s2, m);
        }
        float mm = s * (1.f / 128.f);
        float vv = s2 * (1.f / 128.f) - mm * mm;
        mu[i] = mm;
        rs[i] = rsqrtf(fmaxf(vv, 0.f) + 1e-5f);
    }
}

// normalize h with (mu,rs), store single-bf16 into A tile
__device__ __forceinline__ void write_a(const float (&h)[4][4], const float (&mu)[4], const float (&rs)[4],
                                        __bf16* __restrict__ a_hi, int r0, int fq) {
    #pragma unroll
    for (int i = 0; i < 4; ++i) {
        bf16x4 v;
        #pragma unroll
        for (int jj = 0; jj < 4; ++jj)
            v[jj] = (__bf16)((h[i][jj] - mu[i]) * rs[i]);
        *(bf16x4*)&a_hi[(r0 + i) * ASTRB + fq * 4] = v;
    }
}

// Dense [64,128]x[128,128]: 2x2 tiles/wave. Wave w: rows 32*(w>>2), cols 32*(w&3).
// WLO: add Ah*Bl weight-compensation term (f32-input weights).
template<bool WLO>
__device__ __forceinline__ void mfma_dense(const __bf16* __restrict__ a_hi,
                                           const __bf16* __restrict__ bp,
                                           f32x4 (&acc)[2][2], int lane, int wave)
{
    const int R0  = (wave >> 2) << 5;
    const int Cq2 = (wave & 3) << 1;
    const int c = lane & 15, g = lane >> 4;
    const __bf16* bl = bp + 16384;
    #pragma unroll
    for (int t2 = 0; t2 < 2; ++t2)
        #pragma unroll
        for (int j = 0; j < 2; ++j)
            acc[t2][j] = (f32x4){0.f, 0.f, 0.f, 0.f};
    #pragma unroll
    for (int kc = 0; kc < 4; ++kc) {
        const int ao = kc * 32 + (g << 3);
        bf16x8 a0h = *(const bf16x8*)&a_hi[(R0 + c) * ASTRB + ao];
        bf16x8 a1h = *(const bf16x8*)&a_hi[(R0 + 16 + c) * ASTRB + ao];
        #pragma unroll
        for (int j = 0; j < 2; ++j) {
            const int bi = ((((kc << 3) + Cq2 + j) << 6) + lane) << 3;
            bf16x8 bh = *(const bf16x8*)&bp[bi];
            acc[0][j] = __builtin_amdgcn_mfma_f32_16x16x32_bf16(a0h, bh, acc[0][j], 0, 0, 0);
            acc[1][j] = __builtin_amdgcn_mfma_f32_16x16x32_bf16(a1h, bh, acc[1][j], 0, 0, 0);
            if constexpr (WLO) {
                bf16x8 bv = *(const bf16x8*)&bl[bi];
                acc[0][j] = __builtin_amdgcn_mfma_f32_16x16x32_bf16(a0h, bv, acc[0][j], 0, 0, 0);
                acc[1][j] = __builtin_amdgcn_mfma_f32_16x16x32_bf16(a1h, bv, acc[1][j], 0, 0, 0);
            }
        }
    }
}

// C (2x2 tiles) -> single-bf16 row-major [64][ASTRB]
__device__ __forceinline__ void writeC_rm(const f32x4 (&acc)[2][2],
                                          __bf16* __restrict__ hi, int lane, int wave)
{
    const int R0 = (wave >> 2) << 5;
    const int C0 = (wave & 3) << 5;
    const int c = lane & 15, g4 = (lane >> 4) << 2;
    #pragma unroll
    for (int t2 = 0; t2 < 2; ++t2)
    #pragma unroll
    for (int j = 0; j < 2; ++j)
    #pragma unroll
    for (int r = 0; r < 4; ++r)
        hi[(R0 + 16*t2 + g4 + r) * ASTRB + C0 + 16*j + c] = (__bf16)acc[t2][j][r];
}

// C (2x2 tiles) -> single-bf16 TRANSPOSED vT[d][m]
__device__ __forceinline__ void writeC_vt(const f32x4 (&acc)[2][2],
                                          __bf16* __restrict__ hi, int lane, int wave)
{
    const int R0 = (wave >> 2) << 5;   // m rows
    const int C0 = (wave & 3) << 5;    // d cols
    const int c = lane & 15, g4 = (lane >> 4) << 2;
    #pragma unroll
    for (int t2 = 0; t2 < 2; ++t2)
    #pragma unroll
    for (int j = 0; j < 2; ++j)
    #pragma unroll
    for (int r = 0; r < 4; ++r) {
        int m = R0 + 16*t2 + g4 + r, d = C0 + 16*j + c;
        hi[d * VSTR + m] = (__bf16)acc[t2][j][r];
    }
}

// C (2x2 tiles) -> f32 scratch [64][STR]
__device__ __forceinline__ void writeC_f32(const f32x4 (&acc)[2][2],
                                           float* __restrict__ dst, int lane, int wave)
{
    const int R0 = (wave >> 2) << 5;
    const int C0 = (wave & 3) << 5;
    const int c = lane & 15, g4 = (lane >> 4) << 2;
    #pragma unroll
    for (int t2 = 0; t2 < 2; ++t2)
    #pragma unroll
    for (int j = 0; j < 2; ++j)
    #pragma unroll
    for (int r = 0; r < 4; ++r)
        dst[(R0 + 16*t2 + g4 + r) * STR + C0 + 16*j + c] = acc[t2][j][r];
}

// Pre-split weights into bf16 hi/lo, packed in MFMA B-fragment order.
// Slot layout: wpack[(kind*3 + l)*32768]: [0,16384)=hi frags, [16384,32768)=lo.
template<bool BF16>
__global__ __launch_bounds__(256)
void prep_w(const void* __restrict__ Wq, const void* __restrict__ Wk,
            const void* __restrict__ Wv, const void* __restrict__ Wo,
            const void* __restrict__ Wf, unsigned short* __restrict__ wpack)
{
    {
        const unsigned int* w = (const unsigned int*)Wq;
        bool isbf = true;
        #pragma unroll
        for (int i = 0; i < 16; ++i) {
            unsigned int e = (w[i] >> 7) & 0xFFu;
            isbf = isbf && (e >= 0x60u && e <= 0x7Eu);
        }
        if (isbf != BF16) return;
    }
    const int mat  = blockIdx.x;            // 0..14 = kind*3 + l
    const int kind = mat / 3, l = mat % 3;
    const void* src = (kind == 0) ? Wq : (kind == 1) ? Wk : (kind == 2) ? Wv
                    : (kind == 3) ? Wo : Wf;
    unsigned short* dh = wpack + (size_t)mat * 32768;
    unsigned short* dl = dh + 16384;
    for (int f = threadIdx.x; f < 16384; f += 256) {
        int e    = f & 7;
        int lane = (f >> 3) & 63;
        int tj   = (f >> 9) & 7;
        int kc   = f >> 12;
        int row  = kc * 32 + ((lane >> 4) << 3) + e;
        int col  = tj * 16 + (lane & 15);
        float x  = ldT<BF16>(src, (l * NF + row) * NF + col);
        unsigned short hi = f2bf(x);
        unsigned short lo = f2bf(x - bf2f(hi));
        dh[f] = hi; dl[f] = lo;
    }
}

// a 8704 + q 8704 + k 8704 + vt 9216 + P 8192 = 43520 bf16 + tail
static constexpr size_t SMEM_BYTES =
    (size_t)43520 * 2 + (256 + 48) * 4 + 16;   // 88272 B

template<bool BF16>
__global__ __launch_bounds__(NTH, 1)
void gnn_fused(const void* __restrict__ coords,
               const int* __restrict__ species,
               const unsigned char* __restrict__ maskraw,
               const void* __restrict__ embed,
               const void* __restrict__ Wq,          // dtype signature only
               const void* __restrict__ We,
               const void* __restrict__ bfb,
               const unsigned short* __restrict__ wpack,
               void* __restrict__ out)
{
    constexpr bool WLO = !BF16;   // weight-lo compensation on the f32 path
    // ---- dtype signature check (block-uniform; wrong instantiation exits) ----
    {
        const unsigned int* w = (const unsigned int*)Wq;
        bool isbf = true;
        #pragma unroll
        for (int i = 0; i < 16; ++i) {
            unsigned int e = (w[i] >> 7) & 0xFFu;
            isbf = isbf && (e >= 0x60u && e <= 0x7Eu);
        }
        if (isbf != BF16) return;
    }

    extern __shared__ __bf16 sm[];
    __bf16* a_hi  = sm;                                 // [64][136] hn/msg
    __bf16* q_hi  = sm + 8704;                          // [64][136] q
    __bf16* k_hi  = sm + 17408;                         // [64][136] k
    __bf16* vt_hi = sm + 26112;                         // [128][72] v transposed
    __bf16* p_hi  = sm + 35328;                         // 8 waves x 1024 (2KB swz)
    float*  scratch = (float*)k_hi;                     // spans k+vt: 35840B >= 33792B
    float*  tailf = (float*)(sm + 43520);
    float*  cs   = tailf;                               // 64*4 coords
    float*  wel  = cs + 256;                            // 48 We (f32)
    int*    lenp = (int*)(wel + 48);

    const int t    = threadIdx.x;
    const int b    = blockIdx.x;
    const int fq   = t & 31;
    const int r0   = (t >> 5) * 4;
    const int lane = t & 63;
    const int wave = t >> 6;
    const int c    = lane & 15;
    const int g    = lane >> 4;
    const int g4   = g << 2;
    const int hd   = wave >> 2;          // attention head of this wave
    const int wb   = (wave & 3) << 4;    // attention row base of this wave

    // ---- init: coords, We, mask length ----
    if (t < 64) {
        cs[t * 4 + 0] = ldT<BF16>(coords, (b * NATOM + t) * 3 + 0);
        cs[t * 4 + 1] = ldT<BF16>(coords, (b * NATOM + t) * 3 + 1);
        cs[t * 4 + 2] = ldT<BF16>(coords, (b * NATOM + t) * 3 + 2);
    }
    if (t >= 64 && t < 64 + 42) wel[t - 64] = ldT<BF16>(We, t - 64);
    if (t < 64) {
        unsigned int w0 = *(const unsigned int*)maskraw;
        bool f;
        if (w0 == 1u)               f = ((const int*)maskraw)[b * NATOM + t] != 0;
        else if (w0 == 0x01010101u) f = maskraw[b * NATOM + t] != 0;
        else if (w0 == 0x3F800000u) f = ((const float*)maskraw)[b * NATOM + t] != 0.f;
        else                        f = ((const unsigned short*)maskraw)[b * NATOM + t] != 0;
        unsigned long long bal = __ballot(f);
        if (t == 0) *lenp = (int)__popcll(bal);
    }

    // ---- h0 = embed[species-1] ----
    float h[4][4];
    #pragma unroll
    for (int i = 0; i < 4; ++i) {
        int sp = species[b * NATOM + r0 + i];
        float4 ev = ld4T<BF16>(embed, (sp - 1) * NF + fq * 4);
        h[i][0] = ev.x; h[i][1] = ev.y; h[i][2] = ev.z; h[i][3] = ev.w;
    }
    __syncthreads();
    const int len = *lenp;
    #pragma unroll
    for (int i = 0; i < 4; ++i)
        if (r0 + i >= len) { h[i][0]=0.f; h[i][1]=0.f; h[i][2]=0.f; h[i][3]=0.f; }

    // ---- layer-invariant edge cache: d and exp(-d) per pair (32 regs) ----
    float pdc[4][4], pec[4][4];
    {
        float cnx[4], cny[4], cnz[4];
        #pragma unroll
        for (int r = 0; r < 4; ++r) {
            int n = wb + g4 + r;
            cnx[r] = cs[n*4]; cny[r] = cs[n*4+1]; cnz[r] = cs[n*4+2];
        }
        #pragma unroll
        for (int jt = 0; jt < 4; ++jt) {
            int mc = jt * 16 + c;
            float cmx = cs[mc*4], cmy = cs[mc*4+1], cmz = cs[mc*4+2];
            #pragma unroll
            for (int r = 0; r < 4; ++r) {
                float dx = cnx[r]-cmx, dy = cny[r]-cmy, dz = cnz[r]-cmz;
                float d = fast_sqrt(dx*dx + dy*dy + dz*dz + 1e-12f);
                pdc[jt][r] = d;
                pec[jt][r] = fast_exp(-d);
            }
        }
    }

    float mu[4], rs[4];
    for (int l = 0; l < NLAYER; ++l) {
        // hn = LN(h) -> single-bf16 A tile
        ln_stats(h, mu, rs);
        write_a(h, mu, rs, a_hi, r0, fq);
        __syncthreads();                                        // B1: a ready

        // k, vT, q: all read a, write distinct buffers
        {
            f32x4 kacc[2][2];
            mfma_dense<WLO>(a_hi, (const __bf16*)wpack + (size_t)(3 + l) * 32768, kacc, lane, wave);
            writeC_rm(kacc, k_hi, lane, wave);
        }
        {
            f32x4 vacc[2][2];
            mfma_dense<WLO>(a_hi, (const __bf16*)wpack + (size_t)(6 + l) * 32768, vacc, lane, wave);
            writeC_vt(vacc, vt_hi, lane, wave);
        }
        {
            f32x4 qacc[2][2];
            mfma_dense<WLO>(a_hi, (const __bf16*)wpack + (size_t)(0 + l) * 32768, qacc, lane, wave);
            writeC_rm(qacc, q_hi, lane, wave);
        }
        __syncthreads();                                        // B2: k/vT/q visible

        // ---- logits = (q @ k^T)/8 + bias (NT: k row-major IS B-frag), 1-term ----
        f32x4 lacc[4];
        #pragma unroll
        for (int jt = 0; jt < 4; ++jt) lacc[jt] = (f32x4){0.f,0.f,0.f,0.f};
        #pragma unroll
        for (int kc = 0; kc < 2; ++kc) {
            const int qo = (wb + c) * ASTRB + hd * 64 + kc * 32 + (g << 3);
            bf16x8 qh = *(const bf16x8*)&q_hi[qo];
            #pragma unroll
            for (int jt = 0; jt < 4; ++jt) {
                const int ko = (jt * 16 + c) * ASTRB + hd * 64 + kc * 32 + (g << 3);
                bf16x8 kh = *(const bf16x8*)&k_hi[ko];
                lacc[jt] = __builtin_amdgcn_mfma_f32_16x16x32_bf16(qh, kh, lacc[jt], 0, 0, 0);
            }
        }

        // ---- edge bias (cached d/exp) + masked softmax ----
        float we_[7];
        #pragma unroll
        for (int e = 0; e < 7; ++e) we_[e] = wel[l * 14 + e * 2 + hd];
        float cnx[4], cny[4], cnz[4];
        #pragma unroll
        for (int r = 0; r < 4; ++r) {
            int n = wb + g4 + r;
            cnx[r] = cs[n*4]; cny[r] = cs[n*4+1]; cnz[r] = cs[n*4+2];
        }
        float lg[4][4];
        #pragma unroll
        for (int jt = 0; jt < 4; ++jt) {
            int mc = jt * 16 + c;
            float cmx = cs[mc*4], cmy = cs[mc*4+1], cmz = cs[mc*4+2];
            #pragma unroll
            for (int r = 0; r < 4; ++r) {
                float dx = cnx[r]-cmx, dy = cny[r]-cmy, dz = cnz[r]-cmz;
                float et = pec[jt][r];
                float s1 = fast_rcp(1.f + 7.38905609893065f   * et);
                float s2 = fast_rcp(1.f + 54.598150033144236f * et);
                float s3 = fast_rcp(1.f + 403.4287934927351f  * et);
                lg[jt][r] = lacc[jt][r] * 0.125f
                          + dx*we_[0] + dy*we_[1] + dz*we_[2]
                          + pdc[jt][r]*we_[3]
                          + s1*we_[4] + s2*we_[5] + s3*we_[6];
            }
        }
        float mx[4] = {-3e38f, -3e38f, -3e38f, -3e38f};
        #pragma unroll
        for (int jt = 0; jt < 4; ++jt)
            if (jt * 16 + c < len) {
                #pragma unroll
                for (int r = 0; r < 4; ++r) mx[r] = fmaxf(mx[r], lg[jt][r]);
            }
        #pragma unroll
        for (int r = 0; r < 4; ++r) {
            mx[r] = fmaxf(mx[r], __shfl_xor(mx[r], 1));
            mx[r] = fmaxf(mx[r], __shfl_xor(mx[r], 2));
            mx[r] = fmaxf(mx[r], __shfl_xor(mx[r], 4));
            mx[r] = fmaxf(mx[r], __shfl_xor(mx[r], 8));
        }
        float sv[4] = {0.f, 0.f, 0.f, 0.f};
        #pragma unroll
        for (int jt = 0; jt < 4; ++jt) {
            bool vm = (jt * 16 + c) < len;
            #pragma unroll
            for (int r = 0; r < 4; ++r) {
                float e = vm ? fast_exp(lg[jt][r] - mx[r]) : 0.f;
                lg[jt][r] = e; sv[r] += e;
            }
        }
        #pragma unroll
        for (int r = 0; r < 4; ++r) {
            sv[r] += __shfl_xor(sv[r], 1);
            sv[r] += __shfl_xor(sv[r], 2);
            sv[r] += __shfl_xor(sv[r], 4);
            sv[r] += __shfl_xor(sv[r], 8);
        }
        float inv[4];
        #pragma unroll
        for (int r = 0; r < 4; ++r)
            inv[r] = (wb + g4 + r < len) ? fast_rcp(sv[r]) : 0.f;

        // ---- P stage: single-bf16, own 2KB swizzled slab per wave ----
        // elem (x=0..15 q-row, mm=0..63 k-idx): byte = x*128 + ((mm*2) ^ ((x&7)<<4))
        {
            char* pw = (char*)p_hi + wave * 2048;
            #pragma unroll
            for (int jt = 0; jt < 4; ++jt)
                #pragma unroll
                for (int r = 0; r < 4; ++r) {
                    int x = g4 + r, mm = jt * 16 + c;
                    *(__bf16*)(pw + x * 128 + ((mm * 2) ^ ((x & 7) << 4))) =
                        (__bf16)(lg[jt][r] * inv[r]);
                }
        }
        // no barrier: P write->read is same-wave (lgkmcnt-ordered)

        // ---- msg = P @ V (1-term) ----
        f32x4 macc[4];
        #pragma unroll
        for (int jt = 0; jt < 4; ++jt) macc[jt] = (f32x4){0.f,0.f,0.f,0.f};
        #pragma unroll
        for (int kc = 0; kc < 2; ++kc) {
            const char* pw = (const char*)p_hi + wave * 2048;
            const int m0 = kc * 32 + (g << 3);
            bf16x8 ph = *(const bf16x8*)(pw + c * 128 + ((m0 * 2) ^ ((c & 7) << 4)));
            #pragma unroll
            for (int jt = 0; jt < 4; ++jt) {
                const int vo = (hd * 64 + jt * 16 + c) * VSTR + kc * 32 + (g << 3);
                bf16x8 vh = *(const bf16x8*)&vt_hi[vo];
                macc[jt] = __builtin_amdgcn_mfma_f32_16x16x32_bf16(ph, vh, macc[jt], 0, 0, 0);
            }
        }
        // msg -> a-region single-bf16 (a dead: all a-readers finished pre-B2)
        #pragma unroll
        for (int jt = 0; jt < 4; ++jt)
            #pragma unroll
            for (int r = 0; r < 4; ++r) {
                int idx = (wb + g4 + r) * ASTRB + hd * 64 + jt * 16 + c;
                a_hi[idx] = (__bf16)macc[jt][r];
            }
        __syncthreads();                                        // B3: msg visible; k/vt/P dead

        // h += msg @ Wo (f32 scratch overlays dead k + vt region)
        {
            f32x4 oacc[2][2];
            mfma_dense<WLO>(a_hi, (const __bf16*)wpack + (size_t)(9 + l) * 32768, oacc, lane, wave);
            writeC_f32(oacc, scratch, lane, wave);
        }
        __syncthreads();                                        // B4: scratch visible
        #pragma unroll
        for (int i = 0; i < 4; ++i) {
            float4 ov = *(const float4*)&scratch[(r0 + i) * STR + fq * 4];
            h[i][0] += ov.x; h[i][1] += ov.y; h[i][2] += ov.z; h[i][3] += ov.w;
        }

        // h += tanh(LN(h) @ Wf + bf)
        ln_stats(h, mu, rs);
        write_a(h, mu, rs, a_hi, r0, fq);     // Wo a-reads drained at B4
        __syncthreads();                                        // B5: a ready
        {
            f32x4 facc[2][2];
            mfma_dense<WLO>(a_hi, (const __bf16*)wpack + (size_t)(12 + l) * 32768, facc, lane, wave);
            writeC_f32(facc, scratch, lane, wave);   // h-update scratch reads drained at B5
        }
        __syncthreads();                                        // B6: scratch visible
        {
            float4 bv = ld4T<BF16>(bfb, l * NF + fq * 4);
            #pragma unroll
            for (int i = 0; i < 4; ++i) {
                float z0 = scratch[(r0 + i) * STR + fq * 4 + 0] + bv.x;
                float z1 = scratch[(r0 + i) * STR + fq * 4 + 1] + bv.y;
                float z2 = scratch[(r0 + i) * STR + fq * 4 + 2] + bv.z;
                float z3 = scratch[(r0 + i) * STR + fq * 4 + 3] + bv.w;
                // tanh(z) = 1 - 2/(e^{2z}+1)
                h[i][0] += 1.f - 2.f * fast_rcp(fast_exp(2.f*z0) + 1.f);
                h[i][1] += 1.f - 2.f * fast_rcp(fast_exp(2.f*z1) + 1.f);
                h[i][2] += 1.f - 2.f * fast_rcp(fast_exp(2.f*z2) + 1.f);
                h[i][3] += 1.f - 2.f * fast_rcp(fast_exp(2.f*z3) + 1.f);
            }
        }
        // h *= mask
        #pragma unroll
        for (int i = 0; i < 4; ++i)
            if (r0 + i >= len) { h[i][0]=0.f; h[i][1]=0.f; h[i][2]=0.f; h[i][3]=0.f; }
        // next-layer write_a is safe: Wf a-reads drained at B6; tanh reads
        // scratch (k region), not a; next B1 orders write_a vs k-writes.
    }

    // out = LN(h) in output dtype
    ln_stats(h, mu, rs);
    #pragma unroll
    for (int i = 0; i < 4; ++i) {
        int idx = b * NATOM * NF + (r0 + i) * NF + fq * 4;
        float o0 = (h[i][0]-mu[i])*rs[i], o1 = (h[i][1]-mu[i])*rs[i];
        float o2 = (h[i][2]-mu[i])*rs[i], o3 = (h[i][3]-mu[i])*rs[i];
        if constexpr (BF16) {
            ushort4 o;
            o.x = bfbits(o0); o.y = bfbits(o1); o.z = bfbits(o2); o.w = bfbits(o3);
            *(ushort4*)((unsigned short*)out + idx) = o;
        } else {
            *(float4*)((float*)out + idx) = make_float4(o0, o1, o2, o3);
        }
    }
}

extern "C" void kernel_launch(void* const* d_in, const int* in_sizes, int n_in,
                              void* d_out, int out_size, void* d_ws, size_t ws_size,
                              hipStream_t stream) {
    const void*           coords  = d_in[0];
    const int*            species = (const int*)d_in[1];
    const unsigned char*  maskraw = (const unsigned char*)d_in[2];
    const void*           embed   = d_in[3];
    const void*           Wq      = d_in[4];
    const void*           Wk      = d_in[5];
    const void*           Wv      = d_in[6];
    const void*           Wo      = d_in[7];
    const void*           We      = d_in[8];
    const void*           Wf      = d_in[9];
    const void*           bfb     = d_in[10];

    unsigned short* wpack = (unsigned short*)d_ws;   // 15 * 32768 ushorts = 960 KB

    (void)hipFuncSetAttribute((const void*)gnn_fused<true>,
                              hipFuncAttributeMaxDynamicSharedMemorySize,
                              (int)SMEM_BYTES);
    (void)hipFuncSetAttribute((const void*)gnn_fused<false>,
                              hipFuncAttributeMaxDynamicSharedMemorySize,
                              (int)SMEM_BYTES);

    prep_w<true ><<<dim3(15), dim3(256), 0, stream>>>(Wq, Wk, Wv, Wo, Wf, wpack);
    prep_w<false><<<dim3(15), dim3(256), 0, stream>>>(Wq, Wk, Wv, Wo, Wf, wpack);

    gnn_fused<true ><<<dim3(NBATCH), dim3(NTH), SMEM_BYTES, stream>>>(
        coords, species, maskraw, embed, Wq, We, bfb, wpack, d_out);
    gnn_fused<false><<<dim3(NBATCH), dim3(NTH), SMEM_BYTES, stream>>>(
        coords, species, maskraw, embed, Wq, We, bfb, wpack, d_out);
}

// Round 18
// 394.556 us; speedup vs baseline: 1.2694x; 1.0703x over previous
//
#include <hip/hip_runtime.h>

// NucleiGNN fused forward. Live-path ladder: r13 427 -> r15 388 -> r17 358us
// (hot). r17 verified: 6 barriers/layer (own q/P buffers), d/exp cache.
// This round:
//  (1) q/k/v denses drop the weight-lo term: their outputs are stored as
//      single bf16, so store-quantization (2^-9) dominates what the lo
//      term corrects. Only Wo/Wf (f32 accum into h) keep 2-term.
//      Dense MFMA/layer 160->112, B-loads 80->56.
//  (2) k/v/q fused into ONE dense pass (mfma_dense3): A-frags loaded once
//      per kc (saves 16 ds_read_b128/wave/layer), each A-load feeds 6
//      independent MFMA chains. Acc = 48 f32 regs (fits 128 budget).
// Numerics otherwise = r17 (absmax 0.03125): activations/k/vT/P single-
// bf16, logits/PV 1-term, P in own 2KB swizzled slab/wave.
// Barriers/layer: B1 a-ready -> dense3 kvq -> B2 -> attn+msg->a -> B3 ->
// Wo->scratch -> B4 -> h+=,LN,write_a -> B5 -> Wf->scratch -> B6 -> tanh.

#define NBATCH 2048
#define NATOM  64
#define NF     128
#define NLAYER 3
#define STR    132   // f32 scratch row stride
#define ASTRB  136   // bf16 row-major tile stride
#define VSTR   72    // vT row stride
#define NTH    512

using bf16x8 = __attribute__((ext_vector_type(8))) __bf16;
using bf16x4 = __attribute__((ext_vector_type(4))) __bf16;
using f32x4  = __attribute__((ext_vector_type(4))) float;

__device__ __forceinline__ float bf2f(unsigned short u) {
    union { unsigned int i; float f; } v; v.i = ((unsigned int)u) << 16; return v.f;
}
__device__ __forceinline__ unsigned short f2bf(float f) {
    union { float ff; unsigned int i; } v; v.ff = f;
    unsigned int x = v.i;
    if ((x & 0x7f800000u) == 0x7f800000u) return (unsigned short)(x >> 16);
    return (unsigned short)((x + 0x7fffu + ((x >> 16) & 1u)) >> 16);
}
__device__ __forceinline__ unsigned short bfbits(float x) {
    union { __bf16 b; unsigned short u; } v; v.b = (__bf16)x; return v.u;
}

__device__ __forceinline__ float fast_rcp(float x)  { return __builtin_amdgcn_rcpf(x); }
__device__ __forceinline__ float fast_sqrt(float x) { return __builtin_amdgcn_sqrtf(x); }
__device__ __forceinline__ float fast_exp(float x)  { return __builtin_amdgcn_exp2f(x * 1.4426950408889634f); }

template<bool BF16>
__device__ __forceinline__ float ldT(const void* p, int i) {
    if constexpr (BF16) return bf2f(((const unsigned short*)p)[i]);
    else                return ((const float*)p)[i];
}
template<bool BF16>
__device__ __forceinline__ float4 ld4T(const void* p, int i) {
    if constexpr (BF16) {
        ushort4 v = *(const ushort4*)((const unsigned short*)p + i);
        return make_float4(bf2f(v.x), bf2f(v.y), bf2f(v.z), bf2f(v.w));
    } else {
        return *(const float4*)((const float*)p + i);
    }
}

// LN row statistics; 32 consecutive lanes share a row.
__device__ __forceinline__ void ln_stats(const float (&h)[4][4], float (&mu)[4], float (&rs)[4]) {
    #pragma unroll
    for (int i = 0; i < 4; ++i) {
        float s  = h[i][0] + h[i][1] + h[i][2] + h[i][3];
        float s2 = h[i][0]*h[i][0] + h[i][1]*h[i][1] + h[i][2]*h[i][2] + h[i][3]*h[i][3];
        #pragma unroll
        for (int m = 1; m <= 16; m <<= 1) {
            s  += __shfl_xor(s,  m);
            s2 += __shfl_xor(s2, m);
        }
        float mm = s * (1.f / 128.f);
        float vv = s2 * (1.f / 128.f) - mm * mm;
        mu[i] = mm;
        rs[i] = rsqrtf(fmaxf(vv, 0.f) + 1e-5f);
    }
}

// normalize h with (mu,rs), store single-bf16 into A tile
__device__ __forceinline__ void write_a(const float (&h)[4][4], const float (&mu)[4], const float (&rs)[4],
                                        __bf16* __restrict__ a_hi, int r0, int fq) {
    #pragma unroll
    for (int i = 0; i < 4; ++i) {
        bf16x4 v;
        #pragma unroll
        for (int jj = 0; jj < 4; ++jj)
            v[jj] = (__bf16)((h[i][jj] - mu[i]) * rs[i]);
        *(bf16x4*)&a_hi[(r0 + i) * ASTRB + fq * 4] = v;
    }
}

// Fused k/v/q dense, 1-term each: A-frags loaded ONCE per kc, feed 6 chains.
__device__ __forceinline__ void mfma_dense3(const __bf16* __restrict__ a_hi,
                                            const __bf16* __restrict__ bk,
                                            const __bf16* __restrict__ bv,
                                            const __bf16* __restrict__ bq,
                                            f32x4 (&kacc)[2][2], f32x4 (&vacc)[2][2],
                                            f32x4 (&qacc)[2][2], int lane, int wave)
{
    const int R0  = (wave >> 2) << 5;
    const int Cq2 = (wave & 3) << 1;
    const int c = lane & 15, g = lane >> 4;
    #pragma unroll
    for (int t2 = 0; t2 < 2; ++t2)
        #pragma unroll
        for (int j = 0; j < 2; ++j) {
            kacc[t2][j] = (f32x4){0.f, 0.f, 0.f, 0.f};
            vacc[t2][j] = (f32x4){0.f, 0.f, 0.f, 0.f};
            qacc[t2][j] = (f32x4){0.f, 0.f, 0.f, 0.f};
        }
    #pragma unroll
    for (int kc = 0; kc < 4; ++kc) {
        const int ao = kc * 32 + (g << 3);
        bf16x8 a0h = *(const bf16x8*)&a_hi[(R0 + c) * ASTRB + ao];
        bf16x8 a1h = *(const bf16x8*)&a_hi[(R0 + 16 + c) * ASTRB + ao];
        #pragma unroll
        for (int j = 0; j < 2; ++j) {
            const int bi = ((((kc << 3) + Cq2 + j) << 6) + lane) << 3;
            bf16x8 wk_ = *(const bf16x8*)&bk[bi];
            bf16x8 wv_ = *(const bf16x8*)&bv[bi];
            bf16x8 wq_ = *(const bf16x8*)&bq[bi];
            kacc[0][j] = __builtin_amdgcn_mfma_f32_16x16x32_bf16(a0h, wk_, kacc[0][j], 0, 0, 0);
            vacc[0][j] = __builtin_amdgcn_mfma_f32_16x16x32_bf16(a0h, wv_, vacc[0][j], 0, 0, 0);
            qacc[0][j] = __builtin_amdgcn_mfma_f32_16x16x32_bf16(a0h, wq_, qacc[0][j], 0, 0, 0);
            kacc[1][j] = __builtin_amdgcn_mfma_f32_16x16x32_bf16(a1h, wk_, kacc[1][j], 0, 0, 0);
            vacc[1][j] = __builtin_amdgcn_mfma_f32_16x16x32_bf16(a1h, wv_, vacc[1][j], 0, 0, 0);
            qacc[1][j] = __builtin_amdgcn_mfma_f32_16x16x32_bf16(a1h, wq_, qacc[1][j], 0, 0, 0);
        }
    }
}

// Dense [64,128]x[128,128]: 2x2 tiles/wave. WLO adds Ah*Bl weight term.
template<bool WLO>
__device__ __forceinline__ void mfma_dense(const __bf16* __restrict__ a_hi,
                                           const __bf16* __restrict__ bp,
                                           f32x4 (&acc)[2][2], int lane, int wave)
{
    const int R0  = (wave >> 2) << 5;
    const int Cq2 = (wave & 3) << 1;
    const int c = lane & 15, g = lane >> 4;
    const __bf16* bl = bp + 16384;
    #pragma unroll
    for (int t2 = 0; t2 < 2; ++t2)
        #pragma unroll
        for (int j = 0; j < 2; ++j)
            acc[t2][j] = (f32x4){0.f, 0.f, 0.f, 0.f};
    #pragma unroll
    for (int kc = 0; kc < 4; ++kc) {
        const int ao = kc * 32 + (g << 3);
        bf16x8 a0h = *(const bf16x8*)&a_hi[(R0 + c) * ASTRB + ao];
        bf16x8 a1h = *(const bf16x8*)&a_hi[(R0 + 16 + c) * ASTRB + ao];
        #pragma unroll
        for (int j = 0; j < 2; ++j) {
            const int bi = ((((kc << 3) + Cq2 + j) << 6) + lane) << 3;
            bf16x8 bh = *(const bf16x8*)&bp[bi];
            acc[0][j] = __builtin_amdgcn_mfma_f32_16x16x32_bf16(a0h, bh, acc[0][j], 0, 0, 0);
            acc[1][j] = __builtin_amdgcn_mfma_f32_16x16x32_bf16(a1h, bh, acc[1][j], 0, 0, 0);
            if constexpr (WLO) {
                bf16x8 bv = *(const bf16x8*)&bl[bi];
                acc[0][j] = __builtin_amdgcn_mfma_f32_16x16x32_bf16(a0h, bv, acc[0][j], 0, 0, 0);
                acc[1][j] = __builtin_amdgcn_mfma_f32_16x16x32_bf16(a1h, bv, acc[1][j], 0, 0, 0);
            }
        }
    }
}

// C (2x2 tiles) -> single-bf16 row-major [64][ASTRB]
__device__ __forceinline__ void writeC_rm(const f32x4 (&acc)[2][2],
                                          __bf16* __restrict__ hi, int lane, int wave)
{
    const int R0 = (wave >> 2) << 5;
    const int C0 = (wave & 3) << 5;
    const int c = lane & 15, g4 = (lane >> 4) << 2;
    #pragma unroll
    for (int t2 = 0; t2 < 2; ++t2)
    #pragma unroll
    for (int j = 0; j < 2; ++j)
    #pragma unroll
    for (int r = 0; r < 4; ++r)
        hi[(R0 + 16*t2 + g4 + r) * ASTRB + C0 + 16*j + c] = (__bf16)acc[t2][j][r];
}

// C (2x2 tiles) -> single-bf16 TRANSPOSED vT[d][m]
__device__ __forceinline__ void writeC_vt(const f32x4 (&acc)[2][2],
                                          __bf16* __restrict__ hi, int lane, int wave)
{
    const int R0 = (wave >> 2) << 5;   // m rows
    const int C0 = (wave & 3) << 5;    // d cols
    const int c = lane & 15, g4 = (lane >> 4) << 2;
    #pragma unroll
    for (int t2 = 0; t2 < 2; ++t2)
    #pragma unroll
    for (int j = 0; j < 2; ++j)
    #pragma unroll
    for (int r = 0; r < 4; ++r) {
        int m = R0 + 16*t2 + g4 + r, d = C0 + 16*j + c;
        hi[d * VSTR + m] = (__bf16)acc[t2][j][r];
    }
}

// C (2x2 tiles) -> f32 scratch [64][STR]
__device__ __forceinline__ void writeC_f32(const f32x4 (&acc)[2][2],
                                           float* __restrict__ dst, int lane, int wave)
{
    const int R0 = (wave >> 2) << 5;
    const int C0 = (wave & 3) << 5;
    const int c = lane & 15, g4 = (lane >> 4) << 2;
    #pragma unroll
    for (int t2 = 0; t2 < 2; ++t2)
    #pragma unroll
    for (int j = 0; j < 2; ++j)
    #pragma unroll
    for (int r = 0; r < 4; ++r)
        dst[(R0 + 16*t2 + g4 + r) * STR + C0 + 16*j + c] = acc[t2][j][r];
}

// Pre-split weights into bf16 hi/lo, packed in MFMA B-fragment order.
// Slot layout: wpack[(kind*3 + l)*32768]: [0,16384)=hi frags, [16384,32768)=lo.
template<bool BF16>
__global__ __launch_bounds__(256)
void prep_w(const void* __restrict__ Wq, const void* __restrict__ Wk,
            const void* __restrict__ Wv, const void* __restrict__ Wo,
            const void* __restrict__ Wf, unsigned short* __restrict__ wpack)
{
    {
        const unsigned int* w = (const unsigned int*)Wq;
        bool isbf = true;
        #pragma unroll
        for (int i = 0; i < 16; ++i) {
            unsigned int e = (w[i] >> 7) & 0xFFu;
            isbf = isbf && (e >= 0x60u && e <= 0x7Eu);
        }
        if (isbf != BF16) return;
    }
    const int mat  = blockIdx.x;            // 0..14 = kind*3 + l
    const int kind = mat / 3, l = mat % 3;
    const void* src = (kind == 0) ? Wq : (kind == 1) ? Wk : (kind == 2) ? Wv
                    : (kind == 3) ? Wo : Wf;
    unsigned short* dh = wpack + (size_t)mat * 32768;
    unsigned short* dl = dh + 16384;
    for (int f = threadIdx.x; f < 16384; f += 256) {
        int e    = f & 7;
        int lane = (f >> 3) & 63;
        int tj   = (f >> 9) & 7;
        int kc   = f >> 12;
        int row  = kc * 32 + ((lane >> 4) << 3) + e;
        int col  = tj * 16 + (lane & 15);
        float x  = ldT<BF16>(src, (l * NF + row) * NF + col);
        unsigned short hi = f2bf(x);
        unsigned short lo = f2bf(x - bf2f(hi));
        dh[f] = hi; dl[f] = lo;
    }
}

// a 8704 + q 8704 + k 8704 + vt 9216 + P 8192 = 43520 bf16 + tail
static constexpr size_t SMEM_BYTES =
    (size_t)43520 * 2 + (256 + 48) * 4 + 16;   // 88272 B

template<bool BF16>
__global__ __launch_bounds__(NTH, 1)
void gnn_fused(const void* __restrict__ coords,
               const int* __restrict__ species,
               const unsigned char* __restrict__ maskraw,
               const void* __restrict__ embed,
               const void* __restrict__ Wq,          // dtype signature only
               const void* __restrict__ We,
               const void* __restrict__ bfb,
               const unsigned short* __restrict__ wpack,
               void* __restrict__ out)
{
    constexpr bool WLO = !BF16;   // weight-lo on Wo/Wf (f32-input path)
    // ---- dtype signature check (block-uniform; wrong instantiation exits) ----
    {
        const unsigned int* w = (const unsigned int*)Wq;
        bool isbf = true;
        #pragma unroll
        for (int i = 0; i < 16; ++i) {
            unsigned int e = (w[i] >> 7) & 0xFFu;
            isbf = isbf && (e >= 0x60u && e <= 0x7Eu);
        }
        if (isbf != BF16) return;
    }

    extern __shared__ __bf16 sm[];
    __bf16* a_hi  = sm;                                 // [64][136] hn/msg
    __bf16* q_hi  = sm + 8704;                          // [64][136] q
    __bf16* k_hi  = sm + 17408;                         // [64][136] k
    __bf16* vt_hi = sm + 26112;                         // [128][72] v transposed
    __bf16* p_hi  = sm + 35328;                         // 8 waves x 2KB swz
    float*  scratch = (float*)k_hi;                     // spans k+vt: 35840B >= 33792B
    float*  tailf = (float*)(sm + 43520);
    float*  cs   = tailf;                               // 64*4 coords
    float*  wel  = cs + 256;                            // 48 We (f32)
    int*    lenp = (int*)(wel + 48);

    const int t    = threadIdx.x;
    const int b    = blockIdx.x;
    const int fq   = t & 31;
    const int r0   = (t >> 5) * 4;
    const int lane = t & 63;
    const int wave = t >> 6;
    const int c    = lane & 15;
    const int g    = lane >> 4;
    const int g4   = g << 2;
    const int hd   = wave >> 2;          // attention head of this wave
    const int wb   = (wave & 3) << 4;    // attention row base of this wave

    // ---- init: coords, We, mask length ----
    if (t < 64) {
        cs[t * 4 + 0] = ldT<BF16>(coords, (b * NATOM + t) * 3 + 0);
        cs[t * 4 + 1] = ldT<BF16>(coords, (b * NATOM + t) * 3 + 1);
        cs[t * 4 + 2] = ldT<BF16>(coords, (b * NATOM + t) * 3 + 2);
    }
    if (t >= 64 && t < 64 + 42) wel[t - 64] = ldT<BF16>(We, t - 64);
    if (t < 64) {
        unsigned int w0 = *(const unsigned int*)maskraw;
        bool f;
        if (w0 == 1u)               f = ((const int*)maskraw)[b * NATOM + t] != 0;
        else if (w0 == 0x01010101u) f = maskraw[b * NATOM + t] != 0;
        else if (w0 == 0x3F800000u) f = ((const float*)maskraw)[b * NATOM + t] != 0.f;
        else                        f = ((const unsigned short*)maskraw)[b * NATOM + t] != 0;
        unsigned long long bal = __ballot(f);
        if (t == 0) *lenp = (int)__popcll(bal);
    }

    // ---- h0 = embed[species-1] ----
    float h[4][4];
    #pragma unroll
    for (int i = 0; i < 4; ++i) {
        int sp = species[b * NATOM + r0 + i];
        float4 ev = ld4T<BF16>(embed, (sp - 1) * NF + fq * 4);
        h[i][0] = ev.x; h[i][1] = ev.y; h[i][2] = ev.z; h[i][3] = ev.w;
    }
    __syncthreads();
    const int len = *lenp;
    #pragma unroll
    for (int i = 0; i < 4; ++i)
        if (r0 + i >= len) { h[i][0]=0.f; h[i][1]=0.f; h[i][2]=0.f; h[i][3]=0.f; }

    // ---- layer-invariant edge cache: d and exp(-d) per pair (32 regs) ----
    float pdc[4][4], pec[4][4];
    {
        float cnx[4], cny[4], cnz[4];
        #pragma unroll
        for (int r = 0; r < 4; ++r) {
            int n = wb + g4 + r;
            cnx[r] = cs[n*4]; cny[r] = cs[n*4+1]; cnz[r] = cs[n*4+2];
        }
        #pragma unroll
        for (int jt = 0; jt < 4; ++jt) {
            int mc = jt * 16 + c;
            float cmx = cs[mc*4], cmy = cs[mc*4+1], cmz = cs[mc*4+2];
            #pragma unroll
            for (int r = 0; r < 4; ++r) {
                float dx = cnx[r]-cmx, dy = cny[r]-cmy, dz = cnz[r]-cmz;
                float d = fast_sqrt(dx*dx + dy*dy + dz*dz + 1e-12f);
                pdc[jt][r] = d;
                pec[jt][r] = fast_exp(-d);
            }
        }
    }

    float mu[4], rs[4];
    for (int l = 0; l < NLAYER; ++l) {
        // hn = LN(h) -> single-bf16 A tile
        ln_stats(h, mu, rs);
        write_a(h, mu, rs, a_hi, r0, fq);
        __syncthreads();                                        // B1: a ready

        // k, vT, q: fused dense, A-frags shared, 1-term each
        {
            f32x4 kacc[2][2], vacc[2][2], qacc[2][2];
            mfma_dense3(a_hi,
                        (const __bf16*)wpack + (size_t)(3 + l) * 32768,
                        (const __bf16*)wpack + (size_t)(6 + l) * 32768,
                        (const __bf16*)wpack + (size_t)(0 + l) * 32768,
                        kacc, vacc, qacc, lane, wave);
            writeC_rm(kacc, k_hi, lane, wave);
            writeC_vt(vacc, vt_hi, lane, wave);
            writeC_rm(qacc, q_hi, lane, wave);
        }
        __syncthreads();                                        // B2: k/vT/q visible

        // ---- logits = (q @ k^T)/8 + bias (NT: k row-major IS B-frag), 1-term ----
        f32x4 lacc[4];
        #pragma unroll
        for (int jt = 0; jt < 4; ++jt) lacc[jt] = (f32x4){0.f,0.f,0.f,0.f};
        #pragma unroll
        for (int kc = 0; kc < 2; ++kc) {
            const int qo = (wb + c) * ASTRB + hd * 64 + kc * 32 + (g << 3);
            bf16x8 qh = *(const bf16x8*)&q_hi[qo];
            #pragma unroll
            for (int jt = 0; jt < 4; ++jt) {
                const int ko = (jt * 16 + c) * ASTRB + hd * 64 + kc * 32 + (g << 3);
                bf16x8 kh = *(const bf16x8*)&k_hi[ko];
                lacc[jt] = __builtin_amdgcn_mfma_f32_16x16x32_bf16(qh, kh, lacc[jt], 0, 0, 0);
            }
        }

        // ---- edge bias (cached d/exp) + masked softmax ----
        float we_[7];
        #pragma unroll
        for (int e = 0; e < 7; ++e) we_[e] = wel[l * 14 + e * 2 + hd];
        float cnx[4], cny[4], cnz[4];
        #pragma unroll
        for (int r = 0; r < 4; ++r) {
            int n = wb + g4 + r;
            cnx[r] = cs[n*4]; cny[r] = cs[n*4+1]; cnz[r] = cs[n*4+2];
        }
        float lg[4][4];
        #pragma unroll
        for (int jt = 0; jt < 4; ++jt) {
            int mc = jt * 16 + c;
            float cmx = cs[mc*4], cmy = cs[mc*4+1], cmz = cs[mc*4+2];
            #pragma unroll
            for (int r = 0; r < 4; ++r) {
                float dx = cnx[r]-cmx, dy = cny[r]-cmy, dz = cnz[r]-cmz;
                float et = pec[jt][r];
                float s1 = fast_rcp(1.f + 7.38905609893065f   * et);
                float s2 = fast_rcp(1.f + 54.598150033144236f * et);
                float s3 = fast_rcp(1.f + 403.4287934927351f  * et);
                lg[jt][r] = lacc[jt][r] * 0.125f
                          + dx*we_[0] + dy*we_[1] + dz*we_[2]
                          + pdc[jt][r]*we_[3]
                          + s1*we_[4] + s2*we_[5] + s3*we_[6];
            }
        }
        float mx[4] = {-3e38f, -3e38f, -3e38f, -3e38f};
        #pragma unroll
        for (int jt = 0; jt < 4; ++jt)
            if (jt * 16 + c < len) {
                #pragma unroll
                for (int r = 0; r < 4; ++r) mx[r] = fmaxf(mx[r], lg[jt][r]);
            }
        #pragma unroll
        for (int r = 0; r < 4; ++r) {
            mx[r] = fmaxf(mx[r], __shfl_xor(mx[r], 1));
            mx[r] = fmaxf(mx[r], __shfl_xor(mx[r], 2));
            mx[r] = fmaxf(mx[r], __shfl_xor(mx[r], 4));
            mx[r] = fmaxf(mx[r], __shfl_xor(mx[r], 8));
        }
        float sv[4] = {0.f, 0.f, 0.f, 0.f};
        #pragma unroll
        for (int jt = 0; jt < 4; ++jt) {
            bool vm = (jt * 16 + c) < len;
            #pragma unroll
            for (int r = 0; r < 4; ++r) {
                float e = vm ? fast_exp(lg[jt][r] - mx[r]) : 0.f;
                lg[jt][r] = e; sv[r] += e;
            }
        }
        #pragma unroll
        for (int r = 0; r < 4; ++r) {
            sv[r] += __shfl_xor(sv[r], 1);
            sv[r] += __shfl_xor(sv[r], 2);
            sv[r] += __shfl_xor(sv[r], 4);
            sv[r] += __shfl_xor(sv[r], 8);
        }
        float inv[4];
        #pragma unroll
        for (int r = 0; r < 4; ++r)
            inv[r] = (wb + g4 + r < len) ? fast_rcp(sv[r]) : 0.f;

        // ---- P stage: single-bf16, own 2KB swizzled slab per wave ----
        // elem (x=0..15 q-row, mm=0..63 k-idx): byte = x*128 + ((mm*2) ^ ((x&7)<<4))
        {
            char* pw = (char*)p_hi + wave * 2048;
            #pragma unroll
            for (int jt = 0; jt < 4; ++jt)
                #pragma unroll
                for (int r = 0; r < 4; ++r) {
                    int x = g4 + r, mm = jt * 16 + c;
                    *(__bf16*)(pw + x * 128 + ((mm * 2) ^ ((x & 7) << 4))) =
                        (__bf16)(lg[jt][r] * inv[r]);
                }
        }
        // no barrier: P write->read is same-wave (lgkmcnt-ordered)

        // ---- msg = P @ V (1-term) ----
        f32x4 macc[4];
        #pragma unroll
        for (int jt = 0; jt < 4; ++jt) macc[jt] = (f32x4){0.f,0.f,0.f,0.f};
        #pragma unroll
        for (int kc = 0; kc < 2; ++kc) {
            const char* pw = (const char*)p_hi + wave * 2048;
            const int m0 = kc * 32 + (g << 3);
            bf16x8 ph = *(const bf16x8*)(pw + c * 128 + ((m0 * 2) ^ ((c & 7) << 4)));
            #pragma unroll
            for (int jt = 0; jt < 4; ++jt) {
                const int vo = (hd * 64 + jt * 16 + c) * VSTR + kc * 32 + (g << 3);
                bf16x8 vh = *(const bf16x8*)&vt_hi[vo];
                macc[jt] = __builtin_amdgcn_mfma_f32_16x16x32_bf16(ph, vh, macc[jt], 0, 0, 0);
            }
        }
        // msg -> a-region single-bf16 (a dead: all a-readers finished pre-B2)
        #pragma unroll
        for (int jt = 0; jt < 4; ++jt)
            #pragma unroll
            for (int r = 0; r < 4; ++r) {
                int idx = (wb + g4 + r) * ASTRB + hd * 64 + jt * 16 + c;
                a_hi[idx] = (__bf16)macc[jt][r];
            }
        __syncthreads();                                        // B3: msg visible; k/vt/P dead

        // h += msg @ Wo (2-term; f32 scratch overlays dead k + vt region)
        {
            f32x4 oacc[2][2];
            mfma_dense<WLO>(a_hi, (const __bf16*)wpack + (size_t)(9 + l) * 32768, oacc, lane, wave);
            writeC_f32(oacc, scratch, lane, wave);
        }
        __syncthreads();                                        // B4: scratch visible
        #pragma unroll
        for (int i = 0; i < 4; ++i) {
            float4 ov = *(const float4*)&scratch[(r0 + i) * STR + fq * 4];
            h[i][0] += ov.x; h[i][1] += ov.y; h[i][2] += ov.z; h[i][3] += ov.w;
        }

        // h += tanh(LN(h) @ Wf + bf)  (2-term)
        ln_stats(h, mu, rs);
        write_a(h, mu, rs, a_hi, r0, fq);     // Wo a-reads drained at B4
        __syncthreads();                                        // B5: a ready
        {
            f32x4 facc[2][2];
            mfma_dense<WLO>(a_hi, (const __bf16*)wpack + (size_t)(12 + l) * 32768, facc, lane, wave);
            writeC_f32(facc, scratch, lane, wave);   // h-update scratch reads drained at B5
        }
        __syncthreads();                                        // B6: scratch visible
        {
            float4 bv = ld4T<BF16>(bfb, l * NF + fq * 4);
            #pragma unroll
            for (int i = 0; i < 4; ++i) {
                float z0 = scratch[(r0 + i) * STR + fq * 4 + 0] + bv.x;
                float z1 = scratch[(r0 + i) * STR + fq * 4 + 1] + bv.y;
                float z2 = scratch[(r0 + i) * STR + fq * 4 + 2] + bv.z;
                float z3 = scratch[(r0 + i) * STR + fq * 4 + 3] + bv.w;
                // tanh(z) = 1 - 2/(e^{2z}+1)
                h[i][0] += 1.f - 2.f * fast_rcp(fast_exp(2.f*z0) + 1.f);
                h[i][1] += 1.f - 2.f * fast_rcp(fast_exp(2.f*z1) + 1.f);
                h[i][2] += 1.f - 2.f * fast_rcp(fast_exp(2.f*z2) + 1.f);
                h[i][3] += 1.f - 2.f * fast_rcp(fast_exp(2.f*z3) + 1.f);
            }
        }
        // h *= mask
        #pragma unroll
        for (int i = 0; i < 4; ++i)
            if (r0 + i >= len) { h[i][0]=0.f; h[i][1]=0.f; h[i][2]=0.f; h[i][3]=0.f; }
        // next-layer write_a is safe: Wf a-reads drained at B6; tanh reads
        // scratch (k region), not a; next B1 orders write_a vs k-writes.
    }

    // out = LN(h) in output dtype
    ln_stats(h, mu, rs);
    #pragma unroll
    for (int i = 0; i < 4; ++i) {
        int idx = b * NATOM * NF + (r0 + i) * NF + fq * 4;
        float o0 = (h[i][0]-mu[i])*rs[i], o1 = (h[i][1]-mu[i])*rs[i];
        float o2 = (h[i][2]-mu[i])*rs[i], o3 = (h[i][3]-mu[i])*rs[i];
        if constexpr (BF16) {
            ushort4 o;
            o.x = bfbits(o0); o.y = bfbits(o1); o.z = bfbits(o2); o.w = bfbits(o3);
            *(ushort4*)((unsigned short*)out + idx) = o;
        } else {
            *(float4*)((float*)out + idx) = make_float4(o0, o1, o2, o3);
        }
    }
}

extern "C" void kernel_launch(void* const* d_in, const int* in_sizes, int n_in,
                              void* d_out, int out_size, void* d_ws, size_t ws_size,
                              hipStream_t stream) {
    const void*           coords  = d_in[0];
    const int*            species = (const int*)d_in[1];
    const unsigned char*  maskraw = (const unsigned char*)d_in[2];
    const void*           embed   = d_in[3];
    const void*           Wq      = d_in[4];
    const void*           Wk      = d_in[5];
    const void*           Wv      = d_in[6];
    const void*           Wo      = d_in[7];
    const void*           We      = d_in[8];
    const void*           Wf      = d_in[9];
    const void*           bfb     = d_in[10];

    unsigned short* wpack = (unsigned short*)d_ws;   // 15 * 32768 ushorts = 960 KB

    (void)hipFuncSetAttribute((const void*)gnn_fused<true>,
                              hipFuncAttributeMaxDynamicSharedMemorySize,
                              (int)SMEM_BYTES);
    (void)hipFuncSetAttribute((const void*)gnn_fused<false>,
                              hipFuncAttributeMaxDynamicSharedMemorySize,
                              (int)SMEM_BYTES);

    prep_w<true ><<<dim3(15), dim3(256), 0, stream>>>(Wq, Wk, Wv, Wo, Wf, wpack);
    prep_w<false><<<dim3(15), dim3(256), 0, stream>>>(Wq, Wk, Wv, Wo, Wf, wpack);

    gnn_fused<true ><<<dim3(NBATCH), dim3(NTH), SMEM_BYTES, stream>>>(
        coords, species, maskraw, embed, Wq, We, bfb, wpack, d_out);
    gnn_fused<false><<<dim3(NBATCH), dim3(NTH), SMEM_BYTES, stream>>>(
        coords, species, maskraw, embed, Wq, We, bfb, wpack, d_out);
}

// Round 19
// 360.377 us; speedup vs baseline: 1.3898x; 1.0948x over previous
//
#include <hip/hip_runtime.h>

// NucleiGNN fused forward. Live-path ladder: r13 427 -> r15 388 -> r17 358
// -> r18 327us (hot). r18 verified: fused k/v/q dense (shared A-frags),
// 1-term q/k/v (absmax unchanged at 0.03125 -> store-quantization
// dominates). This round: drop weight-lo from Wo/Wf as well -> ALL
// matmuls 1-term single-bf16. Removes 32 MFMA + 32 B-loads per wave per
// layer from the two serial dense phases. Predicted absmax 0.04-0.06 vs
// threshold 0.0838 (watch; fail -> revert to r18).
// Structure (r17/r18): 6 barriers/layer, own q/P LDS buffers, d/exp(-d)
// register cache, P in 2KB swizzled slab/wave, fast exp/rcp/sqrt.
// Barriers/layer: B1 a-ready -> dense3 kvq -> B2 -> attn+msg->a -> B3 ->
// Wo->scratch -> B4 -> h+=,LN,write_a -> B5 -> Wf->scratch -> B6 -> tanh.

#define NBATCH 2048
#define NATOM  64
#define NF     128
#define NLAYER 3
#define STR    132   // f32 scratch row stride
#define ASTRB  136   // bf16 row-major tile stride
#define VSTR   72    // vT row stride
#define NTH    512

using bf16x8 = __attribute__((ext_vector_type(8))) __bf16;
using bf16x4 = __attribute__((ext_vector_type(4))) __bf16;
using f32x4  = __attribute__((ext_vector_type(4))) float;

__device__ __forceinline__ float bf2f(unsigned short u) {
    union { unsigned int i; float f; } v; v.i = ((unsigned int)u) << 16; return v.f;
}
__device__ __forceinline__ unsigned short f2bf(float f) {
    union { float ff; unsigned int i; } v; v.ff = f;
    unsigned int x = v.i;
    if ((x & 0x7f800000u) == 0x7f800000u) return (unsigned short)(x >> 16);
    return (unsigned short)((x + 0x7fffu + ((x >> 16) & 1u)) >> 16);
}
__device__ __forceinline__ unsigned short bfbits(float x) {
    union { __bf16 b; unsigned short u; } v; v.b = (__bf16)x; return v.u;
}

__device__ __forceinline__ float fast_rcp(float x)  { return __builtin_amdgcn_rcpf(x); }
__device__ __forceinline__ float fast_sqrt(float x) { return __builtin_amdgcn_sqrtf(x); }
__device__ __forceinline__ float fast_exp(float x)  { return __builtin_amdgcn_exp2f(x * 1.4426950408889634f); }

template<bool BF16>
__device__ __forceinline__ float ldT(const void* p, int i) {
    if constexpr (BF16) return bf2f(((const unsigned short*)p)[i]);
    else                return ((const float*)p)[i];
}
template<bool BF16>
__device__ __forceinline__ float4 ld4T(const void* p, int i) {
    if constexpr (BF16) {
        ushort4 v = *(const ushort4*)((const unsigned short*)p + i);
        return make_float4(bf2f(v.x), bf2f(v.y), bf2f(v.z), bf2f(v.w));
    } else {
        return *(const float4*)((const float*)p + i);
    }
}

// LN row statistics; 32 consecutive lanes share a row.
__device__ __forceinline__ void ln_stats(const float (&h)[4][4], float (&mu)[4], float (&rs)[4]) {
    #pragma unroll
    for (int i = 0; i < 4; ++i) {
        float s  = h[i][0] + h[i][1] + h[i][2] + h[i][3];
        float s2 = h[i][0]*h[i][0] + h[i][1]*h[i][1] + h[i][2]*h[i][2] + h[i][3]*h[i][3];
        #pragma unroll
        for (int m = 1; m <= 16; m <<= 1) {
            s  += __shfl_xor(s,  m);
            s2 += __shfl_xor(s2, m);
        }
        float mm = s * (1.f / 128.f);
        float vv = s2 * (1.f / 128.f) - mm * mm;
        mu[i] = mm;
        rs[i] = rsqrtf(fmaxf(vv, 0.f) + 1e-5f);
    }
}

// normalize h with (mu,rs), store single-bf16 into A tile
__device__ __forceinline__ void write_a(const float (&h)[4][4], const float (&mu)[4], const float (&rs)[4],
                                        __bf16* __restrict__ a_hi, int r0, int fq) {
    #pragma unroll
    for (int i = 0; i < 4; ++i) {
        bf16x4 v;
        #pragma unroll
        for (int jj = 0; jj < 4; ++jj)
            v[jj] = (__bf16)((h[i][jj] - mu[i]) * rs[i]);
        *(bf16x4*)&a_hi[(r0 + i) * ASTRB + fq * 4] = v;
    }
}

// Fused k/v/q dense, 1-term each: A-frags loaded ONCE per kc, feed 6 chains.
__device__ __forceinline__ void mfma_dense3(const __bf16* __restrict__ a_hi,
                                            const __bf16* __restrict__ bk,
                                            const __bf16* __restrict__ bv,
                                            const __bf16* __restrict__ bq,
                                            f32x4 (&kacc)[2][2], f32x4 (&vacc)[2][2],
                                            f32x4 (&qacc)[2][2], int lane, int wave)
{
    const int R0  = (wave >> 2) << 5;
    const int Cq2 = (wave & 3) << 1;
    const int c = lane & 15, g = lane >> 4;
    #pragma unroll
    for (int t2 = 0; t2 < 2; ++t2)
        #pragma unroll
        for (int j = 0; j < 2; ++j) {
            kacc[t2][j] = (f32x4){0.f, 0.f, 0.f, 0.f};
            vacc[t2][j] = (f32x4){0.f, 0.f, 0.f, 0.f};
            qacc[t2][j] = (f32x4){0.f, 0.f, 0.f, 0.f};
        }
    #pragma unroll
    for (int kc = 0; kc < 4; ++kc) {
        const int ao = kc * 32 + (g << 3);
        bf16x8 a0h = *(const bf16x8*)&a_hi[(R0 + c) * ASTRB + ao];
        bf16x8 a1h = *(const bf16x8*)&a_hi[(R0 + 16 + c) * ASTRB + ao];
        #pragma unroll
        for (int j = 0; j < 2; ++j) {
            const int bi = ((((kc << 3) + Cq2 + j) << 6) + lane) << 3;
            bf16x8 wk_ = *(const bf16x8*)&bk[bi];
            bf16x8 wv_ = *(const bf16x8*)&bv[bi];
            bf16x8 wq_ = *(const bf16x8*)&bq[bi];
            kacc[0][j] = __builtin_amdgcn_mfma_f32_16x16x32_bf16(a0h, wk_, kacc[0][j], 0, 0, 0);
            vacc[0][j] = __builtin_amdgcn_mfma_f32_16x16x32_bf16(a0h, wv_, vacc[0][j], 0, 0, 0);
            qacc[0][j] = __builtin_amdgcn_mfma_f32_16x16x32_bf16(a0h, wq_, qacc[0][j], 0, 0, 0);
            kacc[1][j] = __builtin_amdgcn_mfma_f32_16x16x32_bf16(a1h, wk_, kacc[1][j], 0, 0, 0);
            vacc[1][j] = __builtin_amdgcn_mfma_f32_16x16x32_bf16(a1h, wv_, vacc[1][j], 0, 0, 0);
            qacc[1][j] = __builtin_amdgcn_mfma_f32_16x16x32_bf16(a1h, wq_, qacc[1][j], 0, 0, 0);
        }
    }
}

// Dense [64,128]x[128,128]: 2x2 tiles/wave, 1-term single-bf16.
__device__ __forceinline__ void mfma_dense(const __bf16* __restrict__ a_hi,
                                           const __bf16* __restrict__ bp,
                                           f32x4 (&acc)[2][2], int lane, int wave)
{
    const int R0  = (wave >> 2) << 5;
    const int Cq2 = (wave & 3) << 1;
    const int c = lane & 15, g = lane >> 4;
    #pragma unroll
    for (int t2 = 0; t2 < 2; ++t2)
        #pragma unroll
        for (int j = 0; j < 2; ++j)
            acc[t2][j] = (f32x4){0.f, 0.f, 0.f, 0.f};
    #pragma unroll
    for (int kc = 0; kc < 4; ++kc) {
        const int ao = kc * 32 + (g << 3);
        bf16x8 a0h = *(const bf16x8*)&a_hi[(R0 + c) * ASTRB + ao];
        bf16x8 a1h = *(const bf16x8*)&a_hi[(R0 + 16 + c) * ASTRB + ao];
        #pragma unroll
        for (int j = 0; j < 2; ++j) {
            const int bi = ((((kc << 3) + Cq2 + j) << 6) + lane) << 3;
            bf16x8 bh = *(const bf16x8*)&bp[bi];
            acc[0][j] = __builtin_amdgcn_mfma_f32_16x16x32_bf16(a0h, bh, acc[0][j], 0, 0, 0);
            acc[1][j] = __builtin_amdgcn_mfma_f32_16x16x32_bf16(a1h, bh, acc[1][j], 0, 0, 0);
        }
    }
}

// C (2x2 tiles) -> single-bf16 row-major [64][ASTRB]
__device__ __forceinline__ void writeC_rm(const f32x4 (&acc)[2][2],
                                          __bf16* __restrict__ hi, int lane, int wave)
{
    const int R0 = (wave >> 2) << 5;
    const int C0 = (wave & 3) << 5;
    const int c = lane & 15, g4 = (lane >> 4) << 2;
    #pragma unroll
    for (int t2 = 0; t2 < 2; ++t2)
    #pragma unroll
    for (int j = 0; j < 2; ++j)
    #pragma unroll
    for (int r = 0; r < 4; ++r)
        hi[(R0 + 16*t2 + g4 + r) * ASTRB + C0 + 16*j + c] = (__bf16)acc[t2][j][r];
}

// C (2x2 tiles) -> single-bf16 TRANSPOSED vT[d][m]
__device__ __forceinline__ void writeC_vt(const f32x4 (&acc)[2][2],
                                          __bf16* __restrict__ hi, int lane, int wave)
{
    const int R0 = (wave >> 2) << 5;   // m rows
    const int C0 = (wave & 3) << 5;    // d cols
    const int c = lane & 15, g4 = (lane >> 4) << 2;
    #pragma unroll
    for (int t2 = 0; t2 < 2; ++t2)
    #pragma unroll
    for (int j = 0; j < 2; ++j)
    #pragma unroll
    for (int r = 0; r < 4; ++r) {
        int m = R0 + 16*t2 + g4 + r, d = C0 + 16*j + c;
        hi[d * VSTR + m] = (__bf16)acc[t2][j][r];
    }
}

// C (2x2 tiles) -> f32 scratch [64][STR]
__device__ __forceinline__ void writeC_f32(const f32x4 (&acc)[2][2],
                                           float* __restrict__ dst, int lane, int wave)
{
    const int R0 = (wave >> 2) << 5;
    const int C0 = (wave & 3) << 5;
    const int c = lane & 15, g4 = (lane >> 4) << 2;
    #pragma unroll
    for (int t2 = 0; t2 < 2; ++t2)
    #pragma unroll
    for (int j = 0; j < 2; ++j)
    #pragma unroll
    for (int r = 0; r < 4; ++r)
        dst[(R0 + 16*t2 + g4 + r) * STR + C0 + 16*j + c] = acc[t2][j][r];
}

// Pre-split weights into bf16 hi/lo, packed in MFMA B-fragment order.
// Slot layout: wpack[(kind*3 + l)*32768]: [0,16384)=hi frags, [16384,32768)=lo.
// (lo plane kept for layout compatibility; unused by the kernel now.)
template<bool BF16>
__global__ __launch_bounds__(256)
void prep_w(const void* __restrict__ Wq, const void* __restrict__ Wk,
            const void* __restrict__ Wv, const void* __restrict__ Wo,
            const void* __restrict__ Wf, unsigned short* __restrict__ wpack)
{
    {
        const unsigned int* w = (const unsigned int*)Wq;
        bool isbf = true;
        #pragma unroll
        for (int i = 0; i < 16; ++i) {
            unsigned int e = (w[i] >> 7) & 0xFFu;
            isbf = isbf && (e >= 0x60u && e <= 0x7Eu);
        }
        if (isbf != BF16) return;
    }
    const int mat  = blockIdx.x;            // 0..14 = kind*3 + l
    const int kind = mat / 3, l = mat % 3;
    const void* src = (kind == 0) ? Wq : (kind == 1) ? Wk : (kind == 2) ? Wv
                    : (kind == 3) ? Wo : Wf;
    unsigned short* dh = wpack + (size_t)mat * 32768;
    unsigned short* dl = dh + 16384;
    for (int f = threadIdx.x; f < 16384; f += 256) {
        int e    = f & 7;
        int lane = (f >> 3) & 63;
        int tj   = (f >> 9) & 7;
        int kc   = f >> 12;
        int row  = kc * 32 + ((lane >> 4) << 3) + e;
        int col  = tj * 16 + (lane & 15);
        float x  = ldT<BF16>(src, (l * NF + row) * NF + col);
        unsigned short hi = f2bf(x);
        unsigned short lo = f2bf(x - bf2f(hi));
        dh[f] = hi; dl[f] = lo;
    }
}

// a 8704 + q 8704 + k 8704 + vt 9216 + P 8192 = 43520 bf16 + tail
static constexpr size_t SMEM_BYTES =
    (size_t)43520 * 2 + (256 + 48) * 4 + 16;   // 88272 B

template<bool BF16>
__global__ __launch_bounds__(NTH, 1)
void gnn_fused(const void* __restrict__ coords,
               const int* __restrict__ species,
               const unsigned char* __restrict__ maskraw,
               const void* __restrict__ embed,
               const void* __restrict__ Wq,          // dtype signature only
               const void* __restrict__ We,
               const void* __restrict__ bfb,
               const unsigned short* __restrict__ wpack,
               void* __restrict__ out)
{
    // ---- dtype signature check (block-uniform; wrong instantiation exits) ----
    {
        const unsigned int* w = (const unsigned int*)Wq;
        bool isbf = true;
        #pragma unroll
        for (int i = 0; i < 16; ++i) {
            unsigned int e = (w[i] >> 7) & 0xFFu;
            isbf = isbf && (e >= 0x60u && e <= 0x7Eu);
        }
        if (isbf != BF16) return;
    }

    extern __shared__ __bf16 sm[];
    __bf16* a_hi  = sm;                                 // [64][136] hn/msg
    __bf16* q_hi  = sm + 8704;                          // [64][136] q
    __bf16* k_hi  = sm + 17408;                         // [64][136] k
    __bf16* vt_hi = sm + 26112;                         // [128][72] v transposed
    __bf16* p_hi  = sm + 35328;                         // 8 waves x 2KB swz
    float*  scratch = (float*)k_hi;                     // spans k+vt: 35840B >= 33792B
    float*  tailf = (float*)(sm + 43520);
    float*  cs   = tailf;                               // 64*4 coords
    float*  wel  = cs + 256;                            // 48 We (f32)
    int*    lenp = (int*)(wel + 48);

    const int t    = threadIdx.x;
    const int b    = blockIdx.x;
    const int fq   = t & 31;
    const int r0   = (t >> 5) * 4;
    const int lane = t & 63;
    const int wave = t >> 6;
    const int c    = lane & 15;
    const int g    = lane >> 4;
    const int g4   = g << 2;
    const int hd   = wave >> 2;          // attention head of this wave
    const int wb   = (wave & 3) << 4;    // attention row base of this wave

    // ---- init: coords, We, mask length ----
    if (t < 64) {
        cs[t * 4 + 0] = ldT<BF16>(coords, (b * NATOM + t) * 3 + 0);
        cs[t * 4 + 1] = ldT<BF16>(coords, (b * NATOM + t) * 3 + 1);
        cs[t * 4 + 2] = ldT<BF16>(coords, (b * NATOM + t) * 3 + 2);
    }
    if (t >= 64 && t < 64 + 42) wel[t - 64] = ldT<BF16>(We, t - 64);
    if (t < 64) {
        unsigned int w0 = *(const unsigned int*)maskraw;
        bool f;
        if (w0 == 1u)               f = ((const int*)maskraw)[b * NATOM + t] != 0;
        else if (w0 == 0x01010101u) f = maskraw[b * NATOM + t] != 0;
        else if (w0 == 0x3F800000u) f = ((const float*)maskraw)[b * NATOM + t] != 0.f;
        else                        f = ((const unsigned short*)maskraw)[b * NATOM + t] != 0;
        unsigned long long bal = __ballot(f);
        if (t == 0) *lenp = (int)__popcll(bal);
    }

    // ---- h0 = embed[species-1] ----
    float h[4][4];
    #pragma unroll
    for (int i = 0; i < 4; ++i) {
        int sp = species[b * NATOM + r0 + i];
        float4 ev = ld4T<BF16>(embed, (sp - 1) * NF + fq * 4);
        h[i][0] = ev.x; h[i][1] = ev.y; h[i][2] = ev.z; h[i][3] = ev.w;
    }
    __syncthreads();
    const int len = *lenp;
    #pragma unroll
    for (int i = 0; i < 4; ++i)
        if (r0 + i >= len) { h[i][0]=0.f; h[i][1]=0.f; h[i][2]=0.f; h[i][3]=0.f; }

    // ---- layer-invariant edge cache: d and exp(-d) per pair (32 regs) ----
    float pdc[4][4], pec[4][4];
    {
        float cnx[4], cny[4], cnz[4];
        #pragma unroll
        for (int r = 0; r < 4; ++r) {
            int n = wb + g4 + r;
            cnx[r] = cs[n*4]; cny[r] = cs[n*4+1]; cnz[r] = cs[n*4+2];
        }
        #pragma unroll
        for (int jt = 0; jt < 4; ++jt) {
            int mc = jt * 16 + c;
            float cmx = cs[mc*4], cmy = cs[mc*4+1], cmz = cs[mc*4+2];
            #pragma unroll
            for (int r = 0; r < 4; ++r) {
                float dx = cnx[r]-cmx, dy = cny[r]-cmy, dz = cnz[r]-cmz;
                float d = fast_sqrt(dx*dx + dy*dy + dz*dz + 1e-12f);
                pdc[jt][r] = d;
                pec[jt][r] = fast_exp(-d);
            }
        }
    }

    float mu[4], rs[4];
    for (int l = 0; l < NLAYER; ++l) {
        // hn = LN(h) -> single-bf16 A tile
        ln_stats(h, mu, rs);
        write_a(h, mu, rs, a_hi, r0, fq);
        __syncthreads();                                        // B1: a ready

        // k, vT, q: fused dense, A-frags shared, 1-term each
        {
            f32x4 kacc[2][2], vacc[2][2], qacc[2][2];
            mfma_dense3(a_hi,
                        (const __bf16*)wpack + (size_t)(3 + l) * 32768,
                        (const __bf16*)wpack + (size_t)(6 + l) * 32768,
                        (const __bf16*)wpack + (size_t)(0 + l) * 32768,
                        kacc, vacc, qacc, lane, wave);
            writeC_rm(kacc, k_hi, lane, wave);
            writeC_vt(vacc, vt_hi, lane, wave);
            writeC_rm(qacc, q_hi, lane, wave);
        }
        __syncthreads();                                        // B2: k/vT/q visible

        // ---- logits = (q @ k^T)/8 + bias (NT: k row-major IS B-frag), 1-term ----
        f32x4 lacc[4];
        #pragma unroll
        for (int jt = 0; jt < 4; ++jt) lacc[jt] = (f32x4){0.f,0.f,0.f,0.f};
        #pragma unroll
        for (int kc = 0; kc < 2; ++kc) {
            const int qo = (wb + c) * ASTRB + hd * 64 + kc * 32 + (g << 3);
            bf16x8 qh = *(const bf16x8*)&q_hi[qo];
            #pragma unroll
            for (int jt = 0; jt < 4; ++jt) {
                const int ko = (jt * 16 + c) * ASTRB + hd * 64 + kc * 32 + (g << 3);
                bf16x8 kh = *(const bf16x8*)&k_hi[ko];
                lacc[jt] = __builtin_amdgcn_mfma_f32_16x16x32_bf16(qh, kh, lacc[jt], 0, 0, 0);
            }
        }

        // ---- edge bias (cached d/exp) + masked softmax ----
        float we_[7];
        #pragma unroll
        for (int e = 0; e < 7; ++e) we_[e] = wel[l * 14 + e * 2 + hd];
        float cnx[4], cny[4], cnz[4];
        #pragma unroll
        for (int r = 0; r < 4; ++r) {
            int n = wb + g4 + r;
            cnx[r] = cs[n*4]; cny[r] = cs[n*4+1]; cnz[r] = cs[n*4+2];
        }
        float lg[4][4];
        #pragma unroll
        for (int jt = 0; jt < 4; ++jt) {
            int mc = jt * 16 + c;
            float cmx = cs[mc*4], cmy = cs[mc*4+1], cmz = cs[mc*4+2];
            #pragma unroll
            for (int r = 0; r < 4; ++r) {
                float dx = cnx[r]-cmx, dy = cny[r]-cmy, dz = cnz[r]-cmz;
                float et = pec[jt][r];
                float s1 = fast_rcp(1.f + 7.38905609893065f   * et);
                float s2 = fast_rcp(1.f + 54.598150033144236f * et);
                float s3 = fast_rcp(1.f + 403.4287934927351f  * et);
                lg[jt][r] = lacc[jt][r] * 0.125f
                          + dx*we_[0] + dy*we_[1] + dz*we_[2]
                          + pdc[jt][r]*we_[3]
                          + s1*we_[4] + s2*we_[5] + s3*we_[6];
            }
        }
        float mx[4] = {-3e38f, -3e38f, -3e38f, -3e38f};
        #pragma unroll
        for (int jt = 0; jt < 4; ++jt)
            if (jt * 16 + c < len) {
                #pragma unroll
                for (int r = 0; r < 4; ++r) mx[r] = fmaxf(mx[r], lg[jt][r]);
            }
        #pragma unroll
        for (int r = 0; r < 4; ++r) {
            mx[r] = fmaxf(mx[r], __shfl_xor(mx[r], 1));
            mx[r] = fmaxf(mx[r], __shfl_xor(mx[r], 2));
            mx[r] = fmaxf(mx[r], __shfl_xor(mx[r], 4));
            mx[r] = fmaxf(mx[r], __shfl_xor(mx[r], 8));
        }
        float sv[4] = {0.f, 0.f, 0.f, 0.f};
        #pragma unroll
        for (int jt = 0; jt < 4; ++jt) {
            bool vm = (jt * 16 + c) < len;
            #pragma unroll
            for (int r = 0; r < 4; ++r) {
                float e = vm ? fast_exp(lg[jt][r] - mx[r]) : 0.f;
                lg[jt][r] = e; sv[r] += e;
            }
        }
        #pragma unroll
        for (int r = 0; r < 4; ++r) {
            sv[r] += __shfl_xor(sv[r], 1);
            sv[r] += __shfl_xor(sv[r], 2);
            sv[r] += __shfl_xor(sv[r], 4);
            sv[r] += __shfl_xor(sv[r], 8);
        }
        float inv[4];
        #pragma unroll
        for (int r = 0; r < 4; ++r)
            inv[r] = (wb + g4 + r < len) ? fast_rcp(sv[r]) : 0.f;

        // ---- P stage: single-bf16, own 2KB swizzled slab per wave ----
        // elem (x=0..15 q-row, mm=0..63 k-idx): byte = x*128 + ((mm*2) ^ ((x&7)<<4))
        {
            char* pw = (char*)p_hi + wave * 2048;
            #pragma unroll
            for (int jt = 0; jt < 4; ++jt)
                #pragma unroll
                for (int r = 0; r < 4; ++r) {
                    int x = g4 + r, mm = jt * 16 + c;
                    *(__bf16*)(pw + x * 128 + ((mm * 2) ^ ((x & 7) << 4))) =
                        (__bf16)(lg[jt][r] * inv[r]);
                }
        }
        // no barrier: P write->read is same-wave (lgkmcnt-ordered)

        // ---- msg = P @ V (1-term) ----
        f32x4 macc[4];
        #pragma unroll
        for (int jt = 0; jt < 4; ++jt) macc[jt] = (f32x4){0.f,0.f,0.f,0.f};
        #pragma unroll
        for (int kc = 0; kc < 2; ++kc) {
            const char* pw = (const char*)p_hi + wave * 2048;
            const int m0 = kc * 32 + (g << 3);
            bf16x8 ph = *(const bf16x8*)(pw + c * 128 + ((m0 * 2) ^ ((c & 7) << 4)));
            #pragma unroll
            for (int jt = 0; jt < 4; ++jt) {
                const int vo = (hd * 64 + jt * 16 + c) * VSTR + kc * 32 + (g << 3);
                bf16x8 vh = *(const bf16x8*)&vt_hi[vo];
                macc[jt] = __builtin_amdgcn_mfma_f32_16x16x32_bf16(ph, vh, macc[jt], 0, 0, 0);
            }
        }
        // msg -> a-region single-bf16 (a dead: all a-readers finished pre-B2)
        #pragma unroll
        for (int jt = 0; jt < 4; ++jt)
            #pragma unroll
            for (int r = 0; r < 4; ++r) {
                int idx = (wb + g4 + r) * ASTRB + hd * 64 + jt * 16 + c;
                a_hi[idx] = (__bf16)macc[jt][r];
            }
        __syncthreads();                                        // B3: msg visible; k/vt/P dead

        // h += msg @ Wo (1-term; f32 scratch overlays dead k + vt region)
        {
            f32x4 oacc[2][2];
            mfma_dense(a_hi, (const __bf16*)wpack + (size_t)(9 + l) * 32768, oacc, lane, wave);
            writeC_f32(oacc, scratch, lane, wave);
        }
        __syncthreads();                                        // B4: scratch visible
        #pragma unroll
        for (int i = 0; i < 4; ++i) {
            float4 ov = *(const float4*)&scratch[(r0 + i) * STR + fq * 4];
            h[i][0] += ov.x; h[i][1] += ov.y; h[i][2] += ov.z; h[i][3] += ov.w;
        }

        // h += tanh(LN(h) @ Wf + bf)  (1-term)
        ln_stats(h, mu, rs);
        write_a(h, mu, rs, a_hi, r0, fq);     // Wo a-reads drained at B4
        __syncthreads();                                        // B5: a ready
        {
            f32x4 facc[2][2];
            mfma_dense(a_hi, (const __bf16*)wpack + (size_t)(12 + l) * 32768, facc, lane, wave);
            writeC_f32(facc, scratch, lane, wave);   // h-update scratch reads drained at B5
        }
        __syncthreads();                                        // B6: scratch visible
        {
            float4 bv = ld4T<BF16>(bfb, l * NF + fq * 4);
            #pragma unroll
            for (int i = 0; i < 4; ++i) {
                float z0 = scratch[(r0 + i) * STR + fq * 4 + 0] + bv.x;
                float z1 = scratch[(r0 + i) * STR + fq * 4 + 1] + bv.y;
                float z2 = scratch[(r0 + i) * STR + fq * 4 + 2] + bv.z;
                float z3 = scratch[(r0 + i) * STR + fq * 4 + 3] + bv.w;
                // tanh(z) = 1 - 2/(e^{2z}+1)
                h[i][0] += 1.f - 2.f * fast_rcp(fast_exp(2.f*z0) + 1.f);
                h[i][1] += 1.f - 2.f * fast_rcp(fast_exp(2.f*z1) + 1.f);
                h[i][2] += 1.f - 2.f * fast_rcp(fast_exp(2.f*z2) + 1.f);
                h[i][3] += 1.f - 2.f * fast_rcp(fast_exp(2.f*z3) + 1.f);
            }
        }
        // h *= mask
        #pragma unroll
        for (int i = 0; i < 4; ++i)
            if (r0 + i >= len) { h[i][0]=0.f; h[i][1]=0.f; h[i][2]=0.f; h[i][3]=0.f; }
        // next-layer write_a is safe: Wf a-reads drained at B6; tanh reads
        // scratch (k region), not a; next B1 orders write_a vs k-writes.
    }

    // out = LN(h) in output dtype
    ln_stats(h, mu, rs);
    #pragma unroll
    for (int i = 0; i < 4; ++i) {
        int idx = b * NATOM * NF + (r0 + i) * NF + fq * 4;
        float o0 = (h[i][0]-mu[i])*rs[i], o1 = (h[i][1]-mu[i])*rs[i];
        float o2 = (h[i][2]-mu[i])*rs[i], o3 = (h[i][3]-mu[i])*rs[i];
        if constexpr (BF16) {
            ushort4 o;
            o.x = bfbits(o0); o.y = bfbits(o1); o.z = bfbits(o2); o.w = bfbits(o3);
            *(ushort4*)((unsigned short*)out + idx) = o;
        } else {
            *(float4*)((float*)out + idx) = make_float4(o0, o1, o2, o3);
        }
    }
}

extern "C" void kernel_launch(void* const* d_in, const int* in_sizes, int n_in,
                              void* d_out, int out_size, void* d_ws, size_t ws_size,
                              hipStream_t stream) {
    const void*           coords  = d_in[0];
    const int*            species = (const int*)d_in[1];
    const unsigned char*  maskraw = (const unsigned char*)d_in[2];
    const void*           embed   = d_in[3];
    const void*           Wq      = d_in[4];
    const void*           Wk      = d_in[5];
    const void*           Wv      = d_in[6];
    const void*           Wo      = d_in[7];
    const void*           We      = d_in[8];
    const void*           Wf      = d_in[9];
    const void*           bfb     = d_in[10];

    unsigned short* wpack = (unsigned short*)d_ws;   // 15 * 32768 ushorts = 960 KB

    (void)hipFuncSetAttribute((const void*)gnn_fused<true>,
                              hipFuncAttributeMaxDynamicSharedMemorySize,
                              (int)SMEM_BYTES);
    (void)hipFuncSetAttribute((const void*)gnn_fused<false>,
                              hipFuncAttributeMaxDynamicSharedMemorySize,
                              (int)SMEM_BYTES);

    prep_w<true ><<<dim3(15), dim3(256), 0, stream>>>(Wq, Wk, Wv, Wo, Wf, wpack);
    prep_w<false><<<dim3(15), dim3(256), 0, stream>>>(Wq, Wk, Wv, Wo, Wf, wpack);

    gnn_fused<true ><<<dim3(NBATCH), dim3(NTH), SMEM_BYTES, stream>>>(
        coords, species, maskraw, embed, Wq, We, bfb, wpack, d_out);
    gnn_fused<false><<<dim3(NBATCH), dim3(NTH), SMEM_BYTES, stream>>>(
        coords, species, maskraw, embed, Wq, We, bfb, wpack, d_out);
}